// Round 11
// baseline (572.015 us; speedup 1.0000x reference)
//
#include <hip/hip_runtime.h>
#include <hip/hip_fp16.h>
#include <math.h>

#define BB 4
#define NN 4096
#define DMM 768
#define HHH 12
#define LHH 4
#define GHH 8
#define DH 64
#define MM 256
#define WW 128
#define NWIN (NN/WW)
#define EPSF 1.0e-4f
#define NRM 0.35355339059327373f   /* 64^-0.25 */
#define NRM2 0.125f                /* 64^-0.5 = NRM^2 */
#define RATIO 0.0625f              /* 256^-0.5 */
#define LN1E4_32 0.28782313662425572f  /* ln(10000)/32 */
#define KSTAB_BLOCKS (BB * GHH * (NN / 64))
#define WGRID ((DMM*DMM)/256)
#define AGRID ((BB*NN*DMM)/1024)

using fp16x8 = __attribute__((ext_vector_type(8))) _Float16;
using f32x4  = __attribute__((ext_vector_type(4))) float;

static __device__ __forceinline__ unsigned short f2h(float x) {
  return __half_as_ushort(__float2half(x));
}
static __device__ __forceinline__ float h2f(unsigned short u) {
  union { unsigned short s; _Float16 f; } cv; cv.s = u;
  return (float)cv.f;
}
/* direct global->LDS 16B DMA (linear LDS dest: wave-uniform base + lane*16) */
static __device__ __forceinline__ void gload16(const unsigned short* g, unsigned short* l) {
  __builtin_amdgcn_global_load_lds(
      (const __attribute__((address_space(1))) void*)g,
      (__attribute__((address_space(3))) void*)l, 16, 0, 0);
}

/* ------- prep fat kernel: w_split x4 | a_split | transpose_proj ------------ */
__global__ __launch_bounds__(256) void prep_all(
    const float* __restrict__ Wq, const float* __restrict__ Wk,
    const float* __restrict__ Wv, const float* __restrict__ Wo,
    const float* __restrict__ x, const float* __restrict__ proj,
    unsigned short* __restrict__ WqH, unsigned short* __restrict__ WkH,
    unsigned short* __restrict__ WvH, unsigned short* __restrict__ WoH,
    unsigned short* __restrict__ xH, unsigned short* __restrict__ xL,
    unsigned short* __restrict__ phh, unsigned short* __restrict__ phl)
{
  int bid = blockIdx.x;
  if (bid < 4 * WGRID) {                       /* w_split: transpose + fp16 */
    const float* W = (bid < WGRID) ? Wq : (bid < 2 * WGRID) ? Wk
                   : (bid < 3 * WGRID) ? Wv : Wo;
    unsigned short* Wh = (bid < WGRID) ? WqH : (bid < 2 * WGRID) ? WkH
                       : (bid < 3 * WGRID) ? WvH : WoH;
    int o = (bid % WGRID) * 256 + threadIdx.x;
    int k = o / DMM, n = o % DMM;
    Wh[(size_t)n * DMM + k] = f2h(W[o]);
    return;
  }
  bid -= 4 * WGRID;
  if (bid < AGRID) {                           /* a_split */
    size_t o = ((size_t)bid * 256 + threadIdx.x) * 4;
    float4 v = *(const float4*)(x + o);
    float f[4] = {v.x, v.y, v.z, v.w};
    unsigned short hi[4], lo[4];
#pragma unroll
    for (int i = 0; i < 4; ++i) {
      hi[i] = f2h(f[i]);
      lo[i] = f2h(f[i] - h2f(hi[i]));
    }
    *(uint2*)(xH + o) = *(uint2*)&hi[0];
    *(uint2*)(xL + o) = *(uint2*)&lo[0];
    return;
  }
  bid -= AGRID;
  {                                            /* transpose_proj (64 blocks) */
    int o = bid * 256 + threadIdx.x;
    int k = o >> 8, m = o & 255;
    float v = proj[m * 64 + k] * NRM;
    unsigned short hh = f2h(v);
    phh[m * 64 + k] = hh;
    phl[m * 64 + k] = f2h(v - h2f(hh));
  }
}

/* ------- split-fp16 MFMA GEMM -> fp32 C (+bias); out-projection ----------- */
__global__ __launch_bounds__(256) void gemm_mfma_pre(
    const unsigned short* __restrict__ Ahi, const unsigned short* __restrict__ Alo,
    const unsigned short* __restrict__ Bhi,
    const float* __restrict__ bias, float* __restrict__ C, int K, int Nc)
{
  __shared__ unsigned short Ah[128][32];
  __shared__ unsigned short Al[128][32];
  __shared__ unsigned short Bh[128][32];

  const int tid = threadIdx.x;
  const int wid = tid >> 6, lane = tid & 63;
  const int quad = lane >> 4, l16 = lane & 15;

  const int nwg = gridDim.x * gridDim.y;
  int hw = blockIdx.y * gridDim.x + blockIdx.x;
  int logical = ((nwg & 7) == 0) ? ((hw & 7) * (nwg >> 3) + (hw >> 3)) : hw;
  const int col0 = (logical % gridDim.x) * 128;
  const int row0 = (logical / gridDim.x) * 128;

  const int wm = (wid & 1) * 64, wn = (wid >> 1) * 64;
  const int sw8 = (quad ^ ((l16 >> 1) & 3)) * 8;

  const int rr = tid >> 2;
  const int cg8 = ((tid & 3) ^ ((tid >> 3) & 3)) * 8;

  f32x4 acc[4][4];
  const f32x4 zf = {0.f, 0.f, 0.f, 0.f};
#pragma unroll
  for (int i = 0; i < 4; ++i)
#pragma unroll
    for (int j = 0; j < 4; ++j) acc[i][j] = zf;

  for (int k0 = 0; k0 < K; k0 += 32) {
    __syncthreads();
    {
      const size_t ro0 = (size_t)(row0 + rr) * K + k0 + cg8;
      const size_t ro1 = (size_t)(row0 + 64 + rr) * K + k0 + cg8;
      const size_t co0 = (size_t)(col0 + rr) * K + k0 + cg8;
      const size_t co1 = (size_t)(col0 + 64 + rr) * K + k0 + cg8;
      unsigned short* la  = &Ah[0][0] + tid * 8;
      unsigned short* lal = &Al[0][0] + tid * 8;
      unsigned short* lb  = &Bh[0][0] + tid * 8;
      gload16(Ahi + ro0, la);
      gload16(Ahi + ro1, la + 2048);
      gload16(Alo + ro0, lal);
      gload16(Alo + ro1, lal + 2048);
      gload16(Bhi + co0, lb);
      gload16(Bhi + co1, lb + 2048);
    }
    __syncthreads();

    fp16x8 afh[4], afl[4], bfh[4];
#pragma unroll
    for (int t = 0; t < 4; ++t) {
      afh[t] = *(const fp16x8*)&Ah[wm + t * 16 + l16][sw8];
      afl[t] = *(const fp16x8*)&Al[wm + t * 16 + l16][sw8];
      bfh[t] = *(const fp16x8*)&Bh[wn + t * 16 + l16][sw8];
    }
#pragma unroll
    for (int ti = 0; ti < 4; ++ti)
#pragma unroll
      for (int tj = 0; tj < 4; ++tj) {
        acc[ti][tj] = __builtin_amdgcn_mfma_f32_16x16x32_f16(afh[ti], bfh[tj], acc[ti][tj], 0, 0, 0);
        acc[ti][tj] = __builtin_amdgcn_mfma_f32_16x16x32_f16(afl[ti], bfh[tj], acc[ti][tj], 0, 0, 0);
      }
  }

  float bv[4] = {0.f, 0.f, 0.f, 0.f};
  if (bias) {
#pragma unroll
    for (int tj = 0; tj < 4; ++tj) bv[tj] = bias[col0 + wn + tj * 16 + l16];
  }
#pragma unroll
  for (int ti = 0; ti < 4; ++ti) {
    const int gr = row0 + wm + ti * 16 + quad * 4;
#pragma unroll
    for (int tj = 0; tj < 4; ++tj) {
      const int gc = col0 + wn + tj * 16 + l16;
      float* cp = C + (size_t)gr * Nc + gc;
#pragma unroll
      for (int r = 0; r < 4; ++r)
        cp[(size_t)r * Nc] = acc[ti][tj][r] + bv[tj];
    }
  }
}

/* ------- split-fp16 MFMA GEMM -> split-fp16 C planes (QKV path) ------------ */
__global__ __launch_bounds__(256) void gemm_mfma_sp(
    const unsigned short* __restrict__ Ahi, const unsigned short* __restrict__ Alo,
    const unsigned short* __restrict__ Bhi,
    unsigned short* __restrict__ Chi, unsigned short* __restrict__ Clo,
    int K, int Nc)
{
  __shared__ unsigned short Ah[128][32];
  __shared__ unsigned short Al[128][32];
  __shared__ unsigned short Bh[128][32];

  const int tid = threadIdx.x;
  const int wid = tid >> 6, lane = tid & 63;
  const int quad = lane >> 4, l16 = lane & 15;

  const int nwg = gridDim.x * gridDim.y;
  int hw = blockIdx.y * gridDim.x + blockIdx.x;
  int logical = ((nwg & 7) == 0) ? ((hw & 7) * (nwg >> 3) + (hw >> 3)) : hw;
  const int col0 = (logical % gridDim.x) * 128;
  const int row0 = (logical / gridDim.x) * 128;

  const int wm = (wid & 1) * 64, wn = (wid >> 1) * 64;
  const int sw8 = (quad ^ ((l16 >> 1) & 3)) * 8;

  const int rr = tid >> 2;
  const int cg8 = ((tid & 3) ^ ((tid >> 3) & 3)) * 8;

  f32x4 acc[4][4];
  const f32x4 zf = {0.f, 0.f, 0.f, 0.f};
#pragma unroll
  for (int i = 0; i < 4; ++i)
#pragma unroll
    for (int j = 0; j < 4; ++j) acc[i][j] = zf;

  for (int k0 = 0; k0 < K; k0 += 32) {
    __syncthreads();
    {
      const size_t ro0 = (size_t)(row0 + rr) * K + k0 + cg8;
      const size_t ro1 = (size_t)(row0 + 64 + rr) * K + k0 + cg8;
      const size_t co0 = (size_t)(col0 + rr) * K + k0 + cg8;
      const size_t co1 = (size_t)(col0 + 64 + rr) * K + k0 + cg8;
      unsigned short* la  = &Ah[0][0] + tid * 8;
      unsigned short* lal = &Al[0][0] + tid * 8;
      unsigned short* lb  = &Bh[0][0] + tid * 8;
      gload16(Ahi + ro0, la);
      gload16(Ahi + ro1, la + 2048);
      gload16(Alo + ro0, lal);
      gload16(Alo + ro1, lal + 2048);
      gload16(Bhi + co0, lb);
      gload16(Bhi + co1, lb + 2048);
    }
    __syncthreads();

    fp16x8 afh[4], afl[4], bfh[4];
#pragma unroll
    for (int t = 0; t < 4; ++t) {
      afh[t] = *(const fp16x8*)&Ah[wm + t * 16 + l16][sw8];
      afl[t] = *(const fp16x8*)&Al[wm + t * 16 + l16][sw8];
      bfh[t] = *(const fp16x8*)&Bh[wn + t * 16 + l16][sw8];
    }
#pragma unroll
    for (int ti = 0; ti < 4; ++ti)
#pragma unroll
      for (int tj = 0; tj < 4; ++tj) {
        acc[ti][tj] = __builtin_amdgcn_mfma_f32_16x16x32_f16(afh[ti], bfh[tj], acc[ti][tj], 0, 0, 0);
        acc[ti][tj] = __builtin_amdgcn_mfma_f32_16x16x32_f16(afl[ti], bfh[tj], acc[ti][tj], 0, 0, 0);
      }
  }

#pragma unroll
  for (int ti = 0; ti < 4; ++ti) {
    const int gr = row0 + wm + ti * 16 + quad * 4;
#pragma unroll
    for (int tj = 0; tj < 4; ++tj) {
      const int gc = col0 + wn + tj * 16 + l16;
#pragma unroll
      for (int r = 0; r < 4; ++r) {
        float c = acc[ti][tj][r];
        unsigned short hi = f2h(c);
        Chi[(size_t)(gr + r) * Nc + gc] = hi;
        if (Clo) Clo[(size_t)(gr + r) * Nc + gc] = f2h(c - h2f(hi));
      }
    }
  }
}

/* ------- mid fat kernel: rot_qk | v_trans | kstab -------------------------- */
__global__ __launch_bounds__(256) void mid_all(
    const unsigned short* __restrict__ QhH, const unsigned short* __restrict__ KhH,
    const unsigned short* __restrict__ KhL, const unsigned short* __restrict__ VhH,
    const unsigned short* __restrict__ phh, const unsigned short* __restrict__ phl,
    unsigned short* __restrict__ Qlh, unsigned short* __restrict__ Klh,
    unsigned short* __restrict__ Vtl, float* __restrict__ stabp)
{
  __shared__ union {
    unsigned short T[64][72];
    struct { unsigned short Khh[64][72]; unsigned short Khl[64][72]; float wred[4]; } ks;
  } M;

  const int tid = threadIdx.x;
  int bid = blockIdx.x;

  if (bid < 256) {                             /* rot_qk */
    int idx = bid * 256 + tid;
    int n = idx & (NN - 1);
    int bh = idx >> 12;
    int b = bh >> 2, h = bh & 3;
    const unsigned short* qs = QhH + ((size_t)(b * NN + n)) * DMM + GHH * DH + h * DH;
    const unsigned short* ks = KhH + ((size_t)(b * NN + n)) * DMM + GHH * DH + h * DH;
    unsigned short qr[64], kr[64];
#pragma unroll
    for (int t = 0; t < 8; ++t) {
      *(uint4*)&qr[t * 8] = *(const uint4*)(qs + t * 8);
      *(uint4*)&kr[t * 8] = *(const uint4*)(ks + t * 8);
    }
    unsigned short qo[64], ko[64];
#pragma unroll
    for (int i = 0; i < 32; ++i) {
      float invf = __expf((float)i * -LN1E4_32);
      float th = (float)n * invf;
      float s, c;
      sincosf(th, &s, &c);
      float q1 = h2f(qr[i]), q2 = h2f(qr[i + 32]);
      float k1 = h2f(kr[i]), k2 = h2f(kr[i + 32]);
      qo[i]      = f2h(fmaf(q1, c, -q2 * s) * NRM2);
      qo[i + 32] = f2h(fmaf(q2, c, q1 * s) * NRM2);
      ko[i]      = f2h(fmaf(k1, c, -k2 * s));
      ko[i + 32] = f2h(fmaf(k2, c, k1 * s));
    }
    unsigned short* qd = Qlh + (size_t)idx * 64;
    unsigned short* kd = Klh + (size_t)idx * 64;
#pragma unroll
    for (int t = 0; t < 8; ++t) {
      *(uint4*)(qd + t * 8) = *(uint4*)&qo[t * 8];
      *(uint4*)(kd + t * 8) = *(uint4*)&ko[t * 8];
    }
    return;
  }
  bid -= 256;
  if (bid < 1024) {                            /* v_trans */
    const int nb = bid & 63, h = (bid >> 6) & 3, b = bid >> 8;
    const int n0 = nb * 64;
    {
      int r = tid >> 2, g = tid & 3;
      const unsigned short* src = VhH + ((size_t)(b * NN + n0 + r)) * DMM + GHH * DH + h * DH + g * 16;
      unsigned short v[16];
      *(uint4*)&v[0] = *(const uint4*)src;
      *(uint4*)&v[8] = *(const uint4*)(src + 8);
#pragma unroll
      for (int j = 0; j < 16; ++j) M.T[g * 16 + j][r] = v[j];
    }
    __syncthreads();
    {
      int d = tid >> 2, g = tid & 3;
      unsigned short* dst = Vtl + ((size_t)(b * LHH + h) * DH + d) * NN + n0 + g * 16;
      *(uint4*)dst       = *(uint4*)&M.T[d][g * 16];
      *(uint4*)(dst + 8) = *(uint4*)&M.T[d][g * 16 + 8];
    }
    return;
  }
  bid -= 1024;                                 /* kstab (2048 blocks) */
  {
    const int wid = tid >> 6, lane = tid & 63;
    const int quad = lane >> 4, l16 = lane & 15;
    const int chunk = bid & 63;
    const int bh = bid >> 6;
    const int b = bh >> 3, h = bh & 7;
    const int n0 = chunk * 64;
    const f32x4 zf = {0.f, 0.f, 0.f, 0.f};

    {
      const int r = tid >> 2, s2 = tid & 3;
      const size_t off = ((size_t)(b * NN + n0 + r)) * DMM + h * DH + s2 * 16;
      *(uint4*)&M.ks.Khh[r][s2 * 16]     = *(const uint4*)(KhH + off);
      *(uint4*)&M.ks.Khh[r][s2 * 16 + 8] = *(const uint4*)(KhH + off + 8);
      *(uint4*)&M.ks.Khl[r][s2 * 16]     = *(const uint4*)(KhL + off);
      *(uint4*)&M.ks.Khl[r][s2 * 16 + 8] = *(const uint4*)(KhL + off + 8);
    }
    __syncthreads();

    const int wn0 = wid * 64;
    f32x4 acc[4][4];
#pragma unroll
    for (int i = 0; i < 4; ++i)
#pragma unroll
      for (int j = 0; j < 4; ++j) acc[i][j] = zf;

#pragma unroll
    for (int ks = 0; ks < 2; ++ks) {
      fp16x8 afh[4], afl[4], bfh[4], bfl[4];
#pragma unroll
      for (int t = 0; t < 4; ++t) {
        afh[t] = *(const fp16x8*)&M.ks.Khh[t * 16 + l16][ks * 32 + quad * 8];
        afl[t] = *(const fp16x8*)&M.ks.Khl[t * 16 + l16][ks * 32 + quad * 8];
        const size_t po = (size_t)(wn0 + t * 16 + l16) * 64 + ks * 32 + quad * 8;
        bfh[t] = *(const fp16x8*)(phh + po);
        bfl[t] = *(const fp16x8*)(phl + po);
      }
#pragma unroll
      for (int mt = 0; mt < 4; ++mt)
#pragma unroll
        for (int nt = 0; nt < 4; ++nt) {
          acc[mt][nt] = __builtin_amdgcn_mfma_f32_16x16x32_f16(afh[mt], bfh[nt], acc[mt][nt], 0, 0, 0);
          acc[mt][nt] = __builtin_amdgcn_mfma_f32_16x16x32_f16(afh[mt], bfl[nt], acc[mt][nt], 0, 0, 0);
          acc[mt][nt] = __builtin_amdgcn_mfma_f32_16x16x32_f16(afl[mt], bfh[nt], acc[mt][nt], 0, 0, 0);
        }
    }

    float mx = -3.4e38f;
#pragma unroll
    for (int mt = 0; mt < 4; ++mt)
#pragma unroll
      for (int nt = 0; nt < 4; ++nt)
#pragma unroll
        for (int r = 0; r < 4; ++r) mx = fmaxf(mx, acc[mt][nt][r]);
#pragma unroll
    for (int off = 32; off; off >>= 1) mx = fmaxf(mx, __shfl_xor(mx, off));
    if (lane == 0) M.ks.wred[wid] = mx;
    __syncthreads();
    if (tid == 0)
      stabp[bid] = fmaxf(fmaxf(M.ks.wred[0], M.ks.wred[1]), fmaxf(M.ks.wred[2], M.ks.wred[3]));
  }
}

/* ---------------- reduce per-block maxima -> scalar stab ------------------- */
__global__ __launch_bounds__(256) void stab_reduce(
    const float* __restrict__ stabp, float* __restrict__ stab_f)
{
  __shared__ float wred[4];
  const int tid = threadIdx.x;
  float m = -3.4e38f;
  for (int i = tid; i < KSTAB_BLOCKS; i += 256) m = fmaxf(m, stabp[i]);
#pragma unroll
  for (int off = 32; off; off >>= 1) m = fmaxf(m, __shfl_xor(m, off));
  if ((tid & 63) == 0) wred[tid >> 6] = m;
  __syncthreads();
  if (tid == 0)
    *stab_f = fmaxf(fmaxf(wred[0], wred[1]), fmaxf(wred[2], wred[3]));
}

/* ---------------- FAVOR: context & k_sum partials via MFMA ----------------- */
__global__ __launch_bounds__(256, 2) void favor_ctx_mfma(
    const unsigned short* __restrict__ KhH, const unsigned short* __restrict__ KhL,
    const unsigned short* __restrict__ VhH,
    const unsigned short* __restrict__ phh, const unsigned short* __restrict__ phl,
    const float* __restrict__ stab_f,
    float* __restrict__ ctxp, float* __restrict__ ksump, int split)
{
  __shared__ unsigned short Khh[64][72];
  __shared__ unsigned short Khl[64][72];
  __shared__ unsigned short Vt_h[64][72];   /* [d][n] */
  __shared__ unsigned short kp_s[256][72];  /* [m][n] */
  __shared__ float diag_s[64];

  const int tid = threadIdx.x;
  const int wid = tid >> 6, lane = tid & 63;
  const int quad = lane >> 4, l16 = lane & 15;
  const int sidx = blockIdx.x % split;
  const int bh = blockIdx.x / split;
  const int b = bh >> 3, h = bh & 7;
  const int rows = NN / split, nch = rows / 64;
  const float stab = *stab_f;
  const int wn0 = wid * 64;
  const f32x4 zf = {0.f, 0.f, 0.f, 0.f};

  f32x4 acc2[4][4];
#pragma unroll
  for (int i = 0; i < 4; ++i)
#pragma unroll
    for (int j = 0; j < 4; ++j) acc2[i][j] = zf;
  float ksacc[4] = {0.f, 0.f, 0.f, 0.f};

  for (int c = 0; c < nch; ++c) {
    const int n0 = sidx * rows + c * 64;
    __syncthreads();
    {
      const int r = tid >> 2, s2 = tid & 3;
      const size_t off = ((size_t)(b * NN + n0 + r)) * DMM + h * DH + s2 * 16;
      unsigned short kh[16], kl[16], vv[16];
      *(uint4*)&kh[0] = *(const uint4*)(KhH + off);
      *(uint4*)&kh[8] = *(const uint4*)(KhH + off + 8);
      *(uint4*)&kl[0] = *(const uint4*)(KhL + off);
      *(uint4*)&kl[8] = *(const uint4*)(KhL + off + 8);
      *(uint4*)&vv[0] = *(const uint4*)(VhH + off);
      *(uint4*)&vv[8] = *(const uint4*)(VhH + off + 8);
      float kq = 0.f;
#pragma unroll
      for (int j = 0; j < 16; ++j) {
        float f = h2f(kh[j]) + h2f(kl[j]);
        kq = fmaf(f, f, kq);
        Vt_h[s2 * 16 + j][r] = vv[j];
      }
      *(uint4*)&Khh[r][s2 * 16]     = *(uint4*)&kh[0];
      *(uint4*)&Khh[r][s2 * 16 + 8] = *(uint4*)&kh[8];
      *(uint4*)&Khl[r][s2 * 16]     = *(uint4*)&kl[0];
      *(uint4*)&Khl[r][s2 * 16 + 8] = *(uint4*)&kl[8];
      kq += __shfl_xor(kq, 1);
      kq += __shfl_xor(kq, 2);
      if (s2 == 0) diag_s[r] = 0.5f * NRM2 * kq;
    }
    __syncthreads();

    f32x4 acc[4][4];
#pragma unroll
    for (int i = 0; i < 4; ++i)
#pragma unroll
      for (int j = 0; j < 4; ++j) acc[i][j] = zf;
#pragma unroll
    for (int ks = 0; ks < 2; ++ks) {
      fp16x8 afh[4], afl[4], bfh[4], bfl[4];
#pragma unroll
      for (int t = 0; t < 4; ++t) {
        afh[t] = *(const fp16x8*)&Khh[t * 16 + l16][ks * 32 + quad * 8];
        afl[t] = *(const fp16x8*)&Khl[t * 16 + l16][ks * 32 + quad * 8];
        const size_t po = (size_t)(wn0 + t * 16 + l16) * 64 + ks * 32 + quad * 8;
        bfh[t] = *(const fp16x8*)(phh + po);
        bfl[t] = *(const fp16x8*)(phl + po);
      }
#pragma unroll
      for (int mt = 0; mt < 4; ++mt)
#pragma unroll
        for (int nt = 0; nt < 4; ++nt) {
          acc[mt][nt] = __builtin_amdgcn_mfma_f32_16x16x32_f16(afh[mt], bfh[nt], acc[mt][nt], 0, 0, 0);
          acc[mt][nt] = __builtin_amdgcn_mfma_f32_16x16x32_f16(afh[mt], bfl[nt], acc[mt][nt], 0, 0, 0);
          acc[mt][nt] = __builtin_amdgcn_mfma_f32_16x16x32_f16(afl[mt], bfh[nt], acc[mt][nt], 0, 0, 0);
        }
    }

    float ks_i[4] = {0.f, 0.f, 0.f, 0.f};
#pragma unroll
    for (int mt = 0; mt < 4; ++mt) {
#pragma unroll
      for (int nt = 0; nt < 4; ++nt) {
        float pv[4];
#pragma unroll
        for (int reg = 0; reg < 4; ++reg) {
          const int n = mt * 16 + quad * 4 + reg;
          float p = RATIO * (__expf(acc[mt][nt][reg] - diag_s[n] - stab) + EPSF);
          pv[reg] = p;
          ks_i[nt] += p;
        }
        __half2 h0 = __floats2half2_rn(pv[0], pv[1]);
        __half2 h1 = __floats2half2_rn(pv[2], pv[3]);
        uint2 w;
        w.x = *(unsigned*)&h0;
        w.y = *(unsigned*)&h1;
        *(uint2*)&kp_s[wn0 + nt * 16 + l16][mt * 16 + quad * 4] = w;
      }
    }
#pragma unroll
    for (int nt = 0; nt < 4; ++nt) {
      float s = ks_i[nt];
      s += __shfl_xor(s, 16);
      s += __shfl_xor(s, 32);
      ksacc[nt] += s;
    }
    __syncthreads();

#pragma unroll
    for (int ks2 = 0; ks2 < 2; ++ks2) {
      fp16x8 ap[4], bv[4];
#pragma unroll
      for (int t = 0; t < 4; ++t) {
        ap[t] = *(const fp16x8*)&kp_s[wn0 + t * 16 + l16][ks2 * 32 + quad * 8];
        bv[t] = *(const fp16x8*)&Vt_h[t * 16 + l16][ks2 * 32 + quad * 8];
      }
#pragma unroll
      for (int mt = 0; mt < 4; ++mt)
#pragma unroll
        for (int nt = 0; nt < 4; ++nt)
          acc2[mt][nt] = __builtin_amdgcn_mfma_f32_16x16x32_f16(ap[mt], bv[nt], acc2[mt][nt], 0, 0, 0);
    }
  }

  {
    float* dst = ctxp + ((size_t)(bh * split + sidx)) * MM * DH;
#pragma unroll
    for (int mt = 0; mt < 4; ++mt)
#pragma unroll
      for (int nt = 0; nt < 4; ++nt) {
        const int m = wn0 + mt * 16 + quad * 4;
        const int d = nt * 16 + l16;
        *(f32x4*)(dst + (size_t)d * MM + m) = acc2[mt][nt];
      }
    if (quad == 0) {
      float* kd = ksump + (size_t)(bh * split + sidx) * MM;
#pragma unroll
      for (int nt = 0; nt < 4; ++nt) kd[wn0 + nt * 16 + l16] = ksacc[nt];
    }
  }
}

/* ---------------- FAVOR: reduce partials -> ctxT fp16 [bh][d][m] + ksum ---- */
__global__ __launch_bounds__(256) void favor_reduce(
    const float* __restrict__ ctxp, const float* __restrict__ ksump,
    unsigned short* __restrict__ ctxT_h, float* __restrict__ ksum, int split)
{
  int i = blockIdx.x * 256 + threadIdx.x;
  if (i < BB * GHH * MM * DH) {
    int bh = i / (MM * DH);
    int md = i % (MM * DH);
    float s = 0.f;
    for (int k = 0; k < split; ++k) s += ctxp[((size_t)(bh * split + k)) * MM * DH + md];
    ctxT_h[i] = f2h(s);
  }
  if (i < BB * GHH * MM) {
    int bh = i / MM, m = i % MM;
    float s = 0.f;
    for (int k = 0; k < split; ++k) s += ksump[(bh * split + k) * MM + m];
    ksum[i] = s;
  }
}

/* ------- attn fat kernel: favor_out (2048 blocks) | local_attn (512) ------- */
struct FOsm {
  union {
    struct { unsigned short Qhh[64][72]; unsigned short Qhl[64][72]; } a;
    unsigned short qp[64][264];
  } u;
  float red[4][64];
  float dred[4][64];
  float diag4[64][4];
  float diag_s[64];
  float dinv_s[64];
  float ksum_s[256];
};
__global__ __launch_bounds__(256, 4) void attn_all(
    const unsigned short* __restrict__ QhH, const unsigned short* __restrict__ QhL,
    const unsigned short* __restrict__ phh, const unsigned short* __restrict__ phl,
    const unsigned short* __restrict__ ctxT_h, const float* __restrict__ ksum,
    const unsigned short* __restrict__ Qlh, const unsigned short* __restrict__ Klh,
    const unsigned short* __restrict__ Vt,
    unsigned short* __restrict__ xH, unsigned short* __restrict__ xL)
{
  __shared__ union {
    FOsm fo;
    unsigned short Pl[4][32][72];
  } S;

  const int tid = threadIdx.x;
  const int wid = tid >> 6, lane = tid & 63;
  const int quad = lane >> 4, l16 = lane & 15;
  const f32x4 zf = {0.f, 0.f, 0.f, 0.f};

  if (blockIdx.x < 2048) {                     /* ---- favor_out ---- */
    const int bh = blockIdx.x >> 6;
    const int chunk = blockIdx.x & 63;
    const int b = bh >> 3, h = bh & 7;
    const int n0 = chunk * 64;

    {
      const int r = tid >> 2, s2 = tid & 3;
      const size_t off = ((size_t)(b * NN + n0 + r)) * DMM + h * DH + s2 * 16;
      unsigned short qh[16], ql[16];
      *(uint4*)&qh[0] = *(const uint4*)(QhH + off);
      *(uint4*)&qh[8] = *(const uint4*)(QhH + off + 8);
      *(uint4*)&ql[0] = *(const uint4*)(QhL + off);
      *(uint4*)&ql[8] = *(const uint4*)(QhL + off + 8);
      float sq = 0.f;
#pragma unroll
      for (int j = 0; j < 16; ++j) {
        float f = h2f(qh[j]) + h2f(ql[j]);
        sq = fmaf(f, f, sq);
      }
      S.fo.diag4[r][s2] = sq;
      *(uint4*)&S.fo.u.a.Qhh[r][s2 * 16]     = *(uint4*)&qh[0];
      *(uint4*)&S.fo.u.a.Qhh[r][s2 * 16 + 8] = *(uint4*)&qh[8];
      *(uint4*)&S.fo.u.a.Qhl[r][s2 * 16]     = *(uint4*)&ql[0];
      *(uint4*)&S.fo.u.a.Qhl[r][s2 * 16 + 8] = *(uint4*)&ql[8];
      S.fo.ksum_s[tid] = ksum[bh * MM + tid];
    }
    __syncthreads();
    if (tid < 64)
      S.fo.diag_s[tid] = 0.5f * NRM2 *
          (S.fo.diag4[tid][0] + S.fo.diag4[tid][1] + S.fo.diag4[tid][2] + S.fo.diag4[tid][3]);

    const int wn0 = wid * 64;
    f32x4 acc[4][4];
#pragma unroll
    for (int i = 0; i < 4; ++i)
#pragma unroll
      for (int j = 0; j < 4; ++j) acc[i][j] = zf;

#pragma unroll
    for (int ks = 0; ks < 2; ++ks) {
      fp16x8 afh[4], afl[4], bfh[4], bfl[4];
#pragma unroll
      for (int t = 0; t < 4; ++t) {
        afh[t] = *(const fp16x8*)&S.fo.u.a.Qhh[t * 16 + l16][ks * 32 + quad * 8];
        afl[t] = *(const fp16x8*)&S.fo.u.a.Qhl[t * 16 + l16][ks * 32 + quad * 8];
        const size_t po = (size_t)(wn0 + t * 16 + l16) * 64 + ks * 32 + quad * 8;
        bfh[t] = *(const fp16x8*)(phh + po);
        bfl[t] = *(const fp16x8*)(phl + po);
      }
#pragma unroll
      for (int mt = 0; mt < 4; ++mt)
#pragma unroll
        for (int nt = 0; nt < 4; ++nt) {
          acc[mt][nt] = __builtin_amdgcn_mfma_f32_16x16x32_f16(afh[mt], bfh[nt], acc[mt][nt], 0, 0, 0);
          acc[mt][nt] = __builtin_amdgcn_mfma_f32_16x16x32_f16(afh[mt], bfl[nt], acc[mt][nt], 0, 0, 0);
          acc[mt][nt] = __builtin_amdgcn_mfma_f32_16x16x32_f16(afl[mt], bfh[nt], acc[mt][nt], 0, 0, 0);
        }
    }

#pragma unroll
    for (int mt = 0; mt < 4; ++mt)
#pragma unroll
      for (int reg = 0; reg < 4; ++reg) {
        float v = fmaxf(fmaxf(acc[mt][0][reg], acc[mt][1][reg]),
                        fmaxf(acc[mt][2][reg], acc[mt][3][reg]));
        v = fmaxf(v, __shfl_xor(v, 1));
        v = fmaxf(v, __shfl_xor(v, 2));
        v = fmaxf(v, __shfl_xor(v, 4));
        v = fmaxf(v, __shfl_xor(v, 8));
        if (l16 == 0) S.fo.red[wid][mt * 16 + quad * 4 + reg] = v;
      }
    __syncthreads();   /* Qhh/Qhl reads drained -> qp aliasing safe */

    float ksv[4];
#pragma unroll
    for (int nt = 0; nt < 4; ++nt) ksv[nt] = S.fo.ksum_s[wn0 + nt * 16 + l16];
#pragma unroll
    for (int mt = 0; mt < 4; ++mt)
#pragma unroll
      for (int reg = 0; reg < 4; ++reg) {
        const int row = mt * 16 + quad * 4 + reg;
        float stab = fmaxf(fmaxf(S.fo.red[0][row], S.fo.red[1][row]),
                           fmaxf(S.fo.red[2][row], S.fo.red[3][row]));
        float base = S.fo.diag_s[row] + stab;
        float dsum = 0.f;
#pragma unroll
        for (int nt = 0; nt < 4; ++nt) {
          float p = RATIO * (__expf(acc[mt][nt][reg] - base) + EPSF);
          acc[mt][nt][reg] = p;
          dsum = fmaf(p, ksv[nt], dsum);
        }
        dsum += __shfl_xor(dsum, 1);
        dsum += __shfl_xor(dsum, 2);
        dsum += __shfl_xor(dsum, 4);
        dsum += __shfl_xor(dsum, 8);
        if (l16 == 0) S.fo.dred[wid][row] = dsum;
#pragma unroll
        for (int nt = 0; nt < 4; ++nt)
          S.fo.u.qp[row][wn0 + nt * 16 + l16] = f2h(acc[mt][nt][reg]);
      }
    __syncthreads();
    if (tid < 64)
      S.fo.dinv_s[tid] = 1.0f / (S.fo.dred[0][tid] + S.fo.dred[1][tid] +
                                 S.fo.dred[2][tid] + S.fo.dred[3][tid]);

    const int wn2 = wid * 16;
    f32x4 acc2[4];
#pragma unroll
    for (int mt = 0; mt < 4; ++mt) acc2[mt] = zf;
#pragma unroll
    for (int ksp = 0; ksp < 8; ++ksp) {
      fp16x8 bv = *(const fp16x8*)(ctxT_h + ((size_t)bh * DH + wn2 + l16) * MM + ksp * 32 + quad * 8);
      fp16x8 ap[4];
#pragma unroll
      for (int mt = 0; mt < 4; ++mt)
        ap[mt] = *(const fp16x8*)&S.fo.u.qp[mt * 16 + l16][ksp * 32 + quad * 8];
#pragma unroll
      for (int mt = 0; mt < 4; ++mt)
        acc2[mt] = __builtin_amdgcn_mfma_f32_16x16x32_f16(ap[mt], bv, acc2[mt], 0, 0, 0);
    }
    __syncthreads();

#pragma unroll
    for (int mt = 0; mt < 4; ++mt)
#pragma unroll
      for (int reg = 0; reg < 4; ++reg) {
        const int row = mt * 16 + quad * 4 + reg;
        float o = acc2[mt][reg] * S.fo.dinv_s[row];
        const size_t base = ((size_t)(b * NN + n0 + row)) * DMM + h * DH + wn2 + l16;
        unsigned short hi = f2h(o);
        xH[base] = hi;
        xL[base] = f2h(o - h2f(hi));
      }
    return;
  }

  /* ---- local attention (flash-style) ---- */
  {
    const int bid2 = blockIdx.x - 2048;
    const int w = bid2 & 31, h = (bid2 >> 5) & 3, b = bid2 >> 7;
    const int bh = b * LHH + h;
    const int qn0 = w * WW + wid * 32;

    fp16x8 Aq[2][2];
#pragma unroll
    for (int mt = 0; mt < 2; ++mt)
#pragma unroll
      for (int ks = 0; ks < 2; ++ks)
        Aq[mt][ks] = *(const fp16x8*)(Qlh + ((size_t)bh * NN + qn0 + mt * 16 + l16) * 64 + ks * 32 + quad * 8);

    float m_run[8], l_run[8];
    f32x4 Oacc[2][4];
#pragma unroll
    for (int r = 0; r < 8; ++r) { m_run[r] = -3.4e38f; l_run[r] = 0.f; }
#pragma unroll
    for (int mt = 0; mt < 2; ++mt)
#pragma unroll
      for (int nt = 0; nt < 4; ++nt) Oacc[mt][nt] = zf;

    const int wb_lo = (w == 0) ? 0 : w - 1;
    const int wb_hi = (w == NWIN - 1) ? w : w + 1;
    for (int wb = wb_lo; wb <= wb_hi; ++wb) {
      for (int half = 0; half < 2; ++half) {
        const int kn0 = wb * WW + half * 64;
        f32x4 sacc[2][4];
#pragma unroll
        for (int mt = 0; mt < 2; ++mt)
#pragma unroll
          for (int nt = 0; nt < 4; ++nt) sacc[mt][nt] = zf;

#pragma unroll
        for (int ks = 0; ks < 2; ++ks) {
          fp16x8 Bk[4];
#pragma unroll
          for (int nt = 0; nt < 4; ++nt)
            Bk[nt] = *(const fp16x8*)(Klh + ((size_t)bh * NN + kn0 + nt * 16 + l16) * 64 + ks * 32 + quad * 8);
#pragma unroll
          for (int mt = 0; mt < 2; ++mt)
#pragma unroll
            for (int nt = 0; nt < 4; ++nt)
              sacc[mt][nt] = __builtin_amdgcn_mfma_f32_16x16x32_f16(Aq[mt][ks], Bk[nt], sacc[mt][nt], 0, 0, 0);
        }

#pragma unroll
        for (int mt = 0; mt < 2; ++mt) {
#pragma unroll
          for (int reg = 0; reg < 4; ++reg) {
            const int r8 = mt * 4 + reg;
            float v = fmaxf(fmaxf(sacc[mt][0][reg], sacc[mt][1][reg]),
                            fmaxf(sacc[mt][2][reg], sacc[mt][3][reg]));
            v = fmaxf(v, __shfl_xor(v, 1));
            v = fmaxf(v, __shfl_xor(v, 2));
            v = fmaxf(v, __shfl_xor(v, 4));
            v = fmaxf(v, __shfl_xor(v, 8));
            float mnew = fmaxf(m_run[r8], v);
            float alpha = __expf(m_run[r8] - mnew);
            m_run[r8] = mnew;
            float ps = 0.f;
#pragma unroll
            for (int nt = 0; nt < 4; ++nt) {
              float p = __expf(sacc[mt][nt][reg] - mnew);
              sacc[mt][nt][reg] = p;
              ps += p;
            }
            ps += __shfl_xor(ps, 1);
            ps += __shfl_xor(ps, 2);
            ps += __shfl_xor(ps, 4);
            ps += __shfl_xor(ps, 8);
            l_run[r8] = l_run[r8] * alpha + ps;
#pragma unroll
            for (int nt = 0; nt < 4; ++nt) Oacc[mt][nt][reg] *= alpha;
          }
        }

#pragma unroll
        for (int mt = 0; mt < 2; ++mt)
#pragma unroll
          for (int nt = 0; nt < 4; ++nt)
#pragma unroll
            for (int reg = 0; reg < 4; ++reg)
              S.Pl[wid][mt * 16 + quad * 4 + reg][nt * 16 + l16] = f2h(sacc[mt][nt][reg]);

#pragma unroll
        for (int kstep = 0; kstep < 2; ++kstep) {
          fp16x8 Ap[2];
#pragma unroll
          for (int mt = 0; mt < 2; ++mt)
            Ap[mt] = *(const fp16x8*)&S.Pl[wid][mt * 16 + l16][kstep * 32 + quad * 8];
          fp16x8 Bv[4];
#pragma unroll
          for (int nt = 0; nt < 4; ++nt)
            Bv[nt] = *(const fp16x8*)(Vt + ((size_t)bh * DH + nt * 16 + l16) * NN + kn0 + kstep * 32 + quad * 8);
#pragma unroll
          for (int mt = 0; mt < 2; ++mt)
#pragma unroll
            for (int nt = 0; nt < 4; ++nt)
              Oacc[mt][nt] = __builtin_amdgcn_mfma_f32_16x16x32_f16(Ap[mt], Bv[nt], Oacc[mt][nt], 0, 0, 0);
        }
      }
    }

#pragma unroll
    for (int mt = 0; mt < 2; ++mt)
#pragma unroll
      for (int reg = 0; reg < 4; ++reg) {
        const float inv = 1.0f / l_run[mt * 4 + reg];
        const int n = qn0 + mt * 16 + quad * 4 + reg;
        const size_t base = ((size_t)(b * NN + n)) * DMM + GHH * DH + h * DH;
#pragma unroll
        for (int nt = 0; nt < 4; ++nt) {
          float o = Oacc[mt][nt][reg] * inv;
          unsigned short hi = f2h(o);
          xH[base + nt * 16 + l16] = hi;
          xL[base + nt * 16 + l16] = f2h(o - h2f(hi));
        }
      }
  }
}

/* ---------------- launcher -------------------------------------------------- */
extern "C" void kernel_launch(void* const* d_in, const int* in_sizes, int n_in,
                              void* d_out, int out_size, void* d_ws, size_t ws_size,
                              hipStream_t stream)
{
  (void)in_sizes; (void)n_in; (void)out_size;
  const float* x    = (const float*)d_in[0];
  const float* Wq   = (const float*)d_in[2];
  const float* Wk   = (const float*)d_in[3];
  const float* Wv   = (const float*)d_in[4];
  const float* Wo   = (const float*)d_in[5];
  const float* bo   = (const float*)d_in[6];
  const float* proj = (const float*)d_in[7];
  float* out = (float*)d_out;

  const size_t WSZ = (size_t)DMM * DMM;
  const size_t XSP = (size_t)BB * NN * DMM;
  const size_t wbuf_f = (4 * WSZ * 2 + 3) / 4;
  const size_t LSZ = (size_t)BB * LHH * NN * DH;
  const size_t lbuf_f = (3 * LSZ * 2 + 3) / 4;
  const size_t fixed_f = (size_t)3 * XSP + (size_t)BB * GHH * MM * DH
                       + (size_t)BB * GHH * MM + KSTAB_BLOCKS + 16 + MM * DH + 16
                       + wbuf_f + 16 + lbuf_f + 16;

  int split = 8;
  for (int s = 32; s >= 8; s >>= 1) {
    size_t part = (size_t)BB * GHH * s * (MM * DH + MM);
    size_t region = part > XSP ? part : XSP;
    if ((fixed_f + region) * 4 <= ws_size) { split = s; break; }
  }
  size_t part_f = (size_t)BB * GHH * split * (MM * DH + MM);
  size_t region_f = XSP > part_f ? XSP : part_f;

  unsigned short* QhH = (unsigned short*)d_ws;
  unsigned short* QhL = QhH + XSP;
  unsigned short* KhH = QhH + 2 * XSP;
  unsigned short* KhL = QhH + 3 * XSP;
  unsigned short* VhH = QhH + 4 * XSP;
  float* region = (float*)d_ws + 3 * XSP;
  float* ctxp  = region;
  float* ksump = ctxp + (size_t)BB * GHH * split * MM * DH;
  unsigned short* xH = (unsigned short*)region;
  unsigned short* xL = xH + XSP;
  float* ctx   = region + region_f;
  unsigned short* ctxT_h = (unsigned short*)ctx;
  float* ksum  = ctx + (size_t)BB * GHH * MM * DH;
  float* stabp = ksum + BB * GHH * MM;
  float* stab_f = stabp + KSTAB_BLOCKS;
  unsigned short* proj_hh = (unsigned short*)(stab_f + 16);
  unsigned short* proj_hl = proj_hh + MM * DH;
  unsigned short* wsp = proj_hl + MM * DH;
  unsigned short* WqH = wsp;
  unsigned short* WkH = wsp + WSZ;
  unsigned short* WvH = wsp + 2 * WSZ;
  unsigned short* WoH = wsp + 3 * WSZ;
  unsigned short* Qlh = wsp + 4 * WSZ;
  unsigned short* Klh = Qlh + LSZ;
  unsigned short* Vtl = Klh + LSZ;

  dim3 blk(256);
  dim3 mg(DMM / 128, (BB * NN) / 128);
  const int PREP_BLOCKS = 4 * WGRID + AGRID + 64;
  const int MID_BLOCKS  = 256 + 1024 + KSTAB_BLOCKS;
  const int ATTN_BLOCKS = 2048 + NWIN * LHH * BB;

  prep_all<<<PREP_BLOCKS, blk, 0, stream>>>(Wq, Wk, Wv, Wo, x, proj,
                                            WqH, WkH, WvH, WoH, xH, xL,
                                            proj_hh, proj_hl);
  gemm_mfma_sp<<<mg, blk, 0, stream>>>(xH, xL, WqH, QhH, QhL, DMM, DMM);
  gemm_mfma_sp<<<mg, blk, 0, stream>>>(xH, xL, WkH, KhH, KhL, DMM, DMM);
  gemm_mfma_sp<<<mg, blk, 0, stream>>>(xH, xL, WvH, VhH, (unsigned short*)0, DMM, DMM);
  mid_all<<<MID_BLOCKS, blk, 0, stream>>>(QhH, KhH, KhL, VhH, proj_hh, proj_hl,
                                          Qlh, Klh, Vtl, stabp);
  stab_reduce<<<1, blk, 0, stream>>>(stabp, stab_f);
  favor_ctx_mfma<<<BB * GHH * split, blk, 0, stream>>>(KhH, KhL, VhH, proj_hh, proj_hl,
                                                       stab_f, ctxp, ksump, split);
  favor_reduce<<<(BB * GHH * MM * DH) / 256, blk, 0, stream>>>(ctxp, ksump, ctxT_h, ksum, split);
  attn_all<<<ATTN_BLOCKS, blk, 0, stream>>>(QhH, QhL, proj_hh, proj_hl, ctxT_h, ksum,
                                            Qlh, Klh, Vtl, xH, xL);
  gemm_mfma_pre<<<mg, blk, 0, stream>>>(xH, xL, WoH, bo, out, DMM, DMM);
}

// Round 12
// 502.916 us; speedup vs baseline: 1.1374x; 1.1374x over previous
//
#include <hip/hip_runtime.h>
#include <hip/hip_fp16.h>
#include <math.h>

#define BB 4
#define NN 4096
#define DMM 768
#define HHH 12
#define LHH 4
#define GHH 8
#define DH 64
#define MM 256
#define WW 128
#define NWIN (NN/WW)
#define EPSF 1.0e-4f
#define NRM 0.35355339059327373f   /* 64^-0.25 */
#define NRM2 0.125f                /* 64^-0.5 = NRM^2 */
#define RATIO 0.0625f              /* 256^-0.5 */
#define LN1E4_32 0.28782313662425572f  /* ln(10000)/32 */
#define KSTAB_BLOCKS (BB * GHH * (NN / 64))
#define WGRID ((DMM*DMM)/256)
#define AGRID ((BB*NN*DMM)/1024)

using fp16x8 = __attribute__((ext_vector_type(8))) _Float16;
using f32x4  = __attribute__((ext_vector_type(4))) float;

static __device__ __forceinline__ unsigned short f2h(float x) {
  return __half_as_ushort(__float2half(x));
}
static __device__ __forceinline__ float h2f(unsigned short u) {
  union { unsigned short s; _Float16 f; } cv; cv.s = u;
  return (float)cv.f;
}
/* direct global->LDS 16B DMA (linear LDS dest: wave-uniform base + lane*16) */
static __device__ __forceinline__ void gload16(const unsigned short* g, unsigned short* l) {
  __builtin_amdgcn_global_load_lds(
      (const __attribute__((address_space(1))) void*)g,
      (__attribute__((address_space(3))) void*)l, 16, 0, 0);
}

/* ------- prep fat kernel: w_split x4 | a_split | transpose_proj ------------ */
__global__ __launch_bounds__(256) void prep_all(
    const float* __restrict__ Wq, const float* __restrict__ Wk,
    const float* __restrict__ Wv, const float* __restrict__ Wo,
    const float* __restrict__ x, const float* __restrict__ proj,
    unsigned short* __restrict__ WqH, unsigned short* __restrict__ WkH,
    unsigned short* __restrict__ WvH, unsigned short* __restrict__ WoH,
    unsigned short* __restrict__ xH, unsigned short* __restrict__ xL,
    unsigned short* __restrict__ phh, unsigned short* __restrict__ phl)
{
  int bid = blockIdx.x;
  if (bid < 4 * WGRID) {                       /* w_split: transpose + fp16 */
    const float* W = (bid < WGRID) ? Wq : (bid < 2 * WGRID) ? Wk
                   : (bid < 3 * WGRID) ? Wv : Wo;
    unsigned short* Wh = (bid < WGRID) ? WqH : (bid < 2 * WGRID) ? WkH
                       : (bid < 3 * WGRID) ? WvH : WoH;
    int o = (bid % WGRID) * 256 + threadIdx.x;
    int k = o / DMM, n = o % DMM;
    Wh[(size_t)n * DMM + k] = f2h(W[o]);
    return;
  }
  bid -= 4 * WGRID;
  if (bid < AGRID) {                           /* a_split */
    size_t o = ((size_t)bid * 256 + threadIdx.x) * 4;
    float4 v = *(const float4*)(x + o);
    float f[4] = {v.x, v.y, v.z, v.w};
    unsigned short hi[4], lo[4];
#pragma unroll
    for (int i = 0; i < 4; ++i) {
      hi[i] = f2h(f[i]);
      lo[i] = f2h(f[i] - h2f(hi[i]));
    }
    *(uint2*)(xH + o) = *(uint2*)&hi[0];
    *(uint2*)(xL + o) = *(uint2*)&lo[0];
    return;
  }
  bid -= AGRID;
  {                                            /* transpose_proj (64 blocks) */
    int o = bid * 256 + threadIdx.x;
    int k = o >> 8, m = o & 255;
    float v = proj[m * 64 + k] * NRM;
    unsigned short hh = f2h(v);
    phh[m * 64 + k] = hh;
    phl[m * 64 + k] = f2h(v - h2f(hh));
  }
}

/* ------- split-fp16 MFMA GEMM -> fp32 C (+bias); out-projection ----------- */
__global__ __launch_bounds__(256) void gemm_mfma_pre(
    const unsigned short* __restrict__ Ahi, const unsigned short* __restrict__ Alo,
    const unsigned short* __restrict__ Bhi,
    const float* __restrict__ bias, float* __restrict__ C, int K, int Nc)
{
  __shared__ unsigned short Ah[128][32];
  __shared__ unsigned short Al[128][32];
  __shared__ unsigned short Bh[128][32];

  const int tid = threadIdx.x;
  const int wid = tid >> 6, lane = tid & 63;
  const int quad = lane >> 4, l16 = lane & 15;

  const int nwg = gridDim.x * gridDim.y;
  int hw = blockIdx.y * gridDim.x + blockIdx.x;
  int logical = ((nwg & 7) == 0) ? ((hw & 7) * (nwg >> 3) + (hw >> 3)) : hw;
  const int col0 = (logical % gridDim.x) * 128;
  const int row0 = (logical / gridDim.x) * 128;

  const int wm = (wid & 1) * 64, wn = (wid >> 1) * 64;
  const int sw8 = (quad ^ ((l16 >> 1) & 3)) * 8;

  const int rr = tid >> 2;
  const int cg8 = ((tid & 3) ^ ((tid >> 3) & 3)) * 8;

  f32x4 acc[4][4];
  const f32x4 zf = {0.f, 0.f, 0.f, 0.f};
#pragma unroll
  for (int i = 0; i < 4; ++i)
#pragma unroll
    for (int j = 0; j < 4; ++j) acc[i][j] = zf;

  for (int k0 = 0; k0 < K; k0 += 32) {
    __syncthreads();
    {
      const size_t ro0 = (size_t)(row0 + rr) * K + k0 + cg8;
      const size_t ro1 = (size_t)(row0 + 64 + rr) * K + k0 + cg8;
      const size_t co0 = (size_t)(col0 + rr) * K + k0 + cg8;
      const size_t co1 = (size_t)(col0 + 64 + rr) * K + k0 + cg8;
      unsigned short* la  = &Ah[0][0] + tid * 8;
      unsigned short* lal = &Al[0][0] + tid * 8;
      unsigned short* lb  = &Bh[0][0] + tid * 8;
      gload16(Ahi + ro0, la);
      gload16(Ahi + ro1, la + 2048);
      gload16(Alo + ro0, lal);
      gload16(Alo + ro1, lal + 2048);
      gload16(Bhi + co0, lb);
      gload16(Bhi + co1, lb + 2048);
    }
    __syncthreads();

    fp16x8 afh[4], afl[4], bfh[4];
#pragma unroll
    for (int t = 0; t < 4; ++t) {
      afh[t] = *(const fp16x8*)&Ah[wm + t * 16 + l16][sw8];
      afl[t] = *(const fp16x8*)&Al[wm + t * 16 + l16][sw8];
      bfh[t] = *(const fp16x8*)&Bh[wn + t * 16 + l16][sw8];
    }
#pragma unroll
    for (int ti = 0; ti < 4; ++ti)
#pragma unroll
      for (int tj = 0; tj < 4; ++tj) {
        acc[ti][tj] = __builtin_amdgcn_mfma_f32_16x16x32_f16(afh[ti], bfh[tj], acc[ti][tj], 0, 0, 0);
        acc[ti][tj] = __builtin_amdgcn_mfma_f32_16x16x32_f16(afl[ti], bfh[tj], acc[ti][tj], 0, 0, 0);
      }
  }

  float bv[4] = {0.f, 0.f, 0.f, 0.f};
  if (bias) {
#pragma unroll
    for (int tj = 0; tj < 4; ++tj) bv[tj] = bias[col0 + wn + tj * 16 + l16];
  }
#pragma unroll
  for (int ti = 0; ti < 4; ++ti) {
    const int gr = row0 + wm + ti * 16 + quad * 4;
#pragma unroll
    for (int tj = 0; tj < 4; ++tj) {
      const int gc = col0 + wn + tj * 16 + l16;
      float* cp = C + (size_t)gr * Nc + gc;
#pragma unroll
      for (int r = 0; r < 4; ++r)
        cp[(size_t)r * Nc] = acc[ti][tj][r] + bv[tj];
    }
  }
}

/* ------- split-fp16 MFMA GEMM -> split-fp16 C planes (QKV path) ------------ */
__global__ __launch_bounds__(256) void gemm_mfma_sp(
    const unsigned short* __restrict__ Ahi, const unsigned short* __restrict__ Alo,
    const unsigned short* __restrict__ Bhi,
    unsigned short* __restrict__ Chi, unsigned short* __restrict__ Clo,
    int K, int Nc)
{
  __shared__ unsigned short Ah[128][32];
  __shared__ unsigned short Al[128][32];
  __shared__ unsigned short Bh[128][32];

  const int tid = threadIdx.x;
  const int wid = tid >> 6, lane = tid & 63;
  const int quad = lane >> 4, l16 = lane & 15;

  const int nwg = gridDim.x * gridDim.y;
  int hw = blockIdx.y * gridDim.x + blockIdx.x;
  int logical = ((nwg & 7) == 0) ? ((hw & 7) * (nwg >> 3) + (hw >> 3)) : hw;
  const int col0 = (logical % gridDim.x) * 128;
  const int row0 = (logical / gridDim.x) * 128;

  const int wm = (wid & 1) * 64, wn = (wid >> 1) * 64;
  const int sw8 = (quad ^ ((l16 >> 1) & 3)) * 8;

  const int rr = tid >> 2;
  const int cg8 = ((tid & 3) ^ ((tid >> 3) & 3)) * 8;

  f32x4 acc[4][4];
  const f32x4 zf = {0.f, 0.f, 0.f, 0.f};
#pragma unroll
  for (int i = 0; i < 4; ++i)
#pragma unroll
    for (int j = 0; j < 4; ++j) acc[i][j] = zf;

  for (int k0 = 0; k0 < K; k0 += 32) {
    __syncthreads();
    {
      const size_t ro0 = (size_t)(row0 + rr) * K + k0 + cg8;
      const size_t ro1 = (size_t)(row0 + 64 + rr) * K + k0 + cg8;
      const size_t co0 = (size_t)(col0 + rr) * K + k0 + cg8;
      const size_t co1 = (size_t)(col0 + 64 + rr) * K + k0 + cg8;
      unsigned short* la  = &Ah[0][0] + tid * 8;
      unsigned short* lal = &Al[0][0] + tid * 8;
      unsigned short* lb  = &Bh[0][0] + tid * 8;
      gload16(Ahi + ro0, la);
      gload16(Ahi + ro1, la + 2048);
      gload16(Alo + ro0, lal);
      gload16(Alo + ro1, lal + 2048);
      gload16(Bhi + co0, lb);
      gload16(Bhi + co1, lb + 2048);
    }
    __syncthreads();

    fp16x8 afh[4], afl[4], bfh[4];
#pragma unroll
    for (int t = 0; t < 4; ++t) {
      afh[t] = *(const fp16x8*)&Ah[wm + t * 16 + l16][sw8];
      afl[t] = *(const fp16x8*)&Al[wm + t * 16 + l16][sw8];
      bfh[t] = *(const fp16x8*)&Bh[wn + t * 16 + l16][sw8];
    }
#pragma unroll
    for (int ti = 0; ti < 4; ++ti)
#pragma unroll
      for (int tj = 0; tj < 4; ++tj) {
        acc[ti][tj] = __builtin_amdgcn_mfma_f32_16x16x32_f16(afh[ti], bfh[tj], acc[ti][tj], 0, 0, 0);
        acc[ti][tj] = __builtin_amdgcn_mfma_f32_16x16x32_f16(afl[ti], bfh[tj], acc[ti][tj], 0, 0, 0);
      }
  }

#pragma unroll
  for (int ti = 0; ti < 4; ++ti) {
    const int gr = row0 + wm + ti * 16 + quad * 4;
#pragma unroll
    for (int tj = 0; tj < 4; ++tj) {
      const int gc = col0 + wn + tj * 16 + l16;
#pragma unroll
      for (int r = 0; r < 4; ++r) {
        float c = acc[ti][tj][r];
        unsigned short hi = f2h(c);
        Chi[(size_t)(gr + r) * Nc + gc] = hi;
        if (Clo) Clo[(size_t)(gr + r) * Nc + gc] = f2h(c - h2f(hi));
      }
    }
  }
}

/* ------- mid fat kernel: rot_qk | v_trans | kstab -------------------------- */
__global__ __launch_bounds__(256) void mid_all(
    const unsigned short* __restrict__ QhH, const unsigned short* __restrict__ KhH,
    const unsigned short* __restrict__ KhL, const unsigned short* __restrict__ VhH,
    const unsigned short* __restrict__ phh, const unsigned short* __restrict__ phl,
    unsigned short* __restrict__ Qlh, unsigned short* __restrict__ Klh,
    unsigned short* __restrict__ Vtl, float* __restrict__ stabp)
{
  __shared__ union {
    unsigned short T[64][72];
    struct { unsigned short Khh[64][72]; unsigned short Khl[64][72]; float wred[4]; } ks;
  } M;

  const int tid = threadIdx.x;
  int bid = blockIdx.x;

  if (bid < 256) {                             /* rot_qk */
    int idx = bid * 256 + tid;
    int n = idx & (NN - 1);
    int bh = idx >> 12;
    int b = bh >> 2, h = bh & 3;
    const unsigned short* qs = QhH + ((size_t)(b * NN + n)) * DMM + GHH * DH + h * DH;
    const unsigned short* ks = KhH + ((size_t)(b * NN + n)) * DMM + GHH * DH + h * DH;
    unsigned short qr[64], kr[64];
#pragma unroll
    for (int t = 0; t < 8; ++t) {
      *(uint4*)&qr[t * 8] = *(const uint4*)(qs + t * 8);
      *(uint4*)&kr[t * 8] = *(const uint4*)(ks + t * 8);
    }
    unsigned short qo[64], ko[64];
#pragma unroll
    for (int i = 0; i < 32; ++i) {
      float invf = __expf((float)i * -LN1E4_32);
      float th = (float)n * invf;
      float s, c;
      sincosf(th, &s, &c);
      float q1 = h2f(qr[i]), q2 = h2f(qr[i + 32]);
      float k1 = h2f(kr[i]), k2 = h2f(kr[i + 32]);
      qo[i]      = f2h(fmaf(q1, c, -q2 * s) * NRM2);
      qo[i + 32] = f2h(fmaf(q2, c, q1 * s) * NRM2);
      ko[i]      = f2h(fmaf(k1, c, -k2 * s));
      ko[i + 32] = f2h(fmaf(k2, c, k1 * s));
    }
    unsigned short* qd = Qlh + (size_t)idx * 64;
    unsigned short* kd = Klh + (size_t)idx * 64;
#pragma unroll
    for (int t = 0; t < 8; ++t) {
      *(uint4*)(qd + t * 8) = *(uint4*)&qo[t * 8];
      *(uint4*)(kd + t * 8) = *(uint4*)&ko[t * 8];
    }
    return;
  }
  bid -= 256;
  if (bid < 1024) {                            /* v_trans */
    const int nb = bid & 63, h = (bid >> 6) & 3, b = bid >> 8;
    const int n0 = nb * 64;
    {
      int r = tid >> 2, g = tid & 3;
      const unsigned short* src = VhH + ((size_t)(b * NN + n0 + r)) * DMM + GHH * DH + h * DH + g * 16;
      unsigned short v[16];
      *(uint4*)&v[0] = *(const uint4*)src;
      *(uint4*)&v[8] = *(const uint4*)(src + 8);
#pragma unroll
      for (int j = 0; j < 16; ++j) M.T[g * 16 + j][r] = v[j];
    }
    __syncthreads();
    {
      int d = tid >> 2, g = tid & 3;
      unsigned short* dst = Vtl + ((size_t)(b * LHH + h) * DH + d) * NN + n0 + g * 16;
      *(uint4*)dst       = *(uint4*)&M.T[d][g * 16];
      *(uint4*)(dst + 8) = *(uint4*)&M.T[d][g * 16 + 8];
    }
    return;
  }
  bid -= 1024;                                 /* kstab (2048 blocks) */
  {
    const int wid = tid >> 6, lane = tid & 63;
    const int quad = lane >> 4, l16 = lane & 15;
    const int chunk = bid & 63;
    const int bh = bid >> 6;
    const int b = bh >> 3, h = bh & 7;
    const int n0 = chunk * 64;
    const f32x4 zf = {0.f, 0.f, 0.f, 0.f};

    {
      const int r = tid >> 2, s2 = tid & 3;
      const size_t off = ((size_t)(b * NN + n0 + r)) * DMM + h * DH + s2 * 16;
      *(uint4*)&M.ks.Khh[r][s2 * 16]     = *(const uint4*)(KhH + off);
      *(uint4*)&M.ks.Khh[r][s2 * 16 + 8] = *(const uint4*)(KhH + off + 8);
      *(uint4*)&M.ks.Khl[r][s2 * 16]     = *(const uint4*)(KhL + off);
      *(uint4*)&M.ks.Khl[r][s2 * 16 + 8] = *(const uint4*)(KhL + off + 8);
    }
    __syncthreads();

    const int wn0 = wid * 64;
    f32x4 acc[4][4];
#pragma unroll
    for (int i = 0; i < 4; ++i)
#pragma unroll
      for (int j = 0; j < 4; ++j) acc[i][j] = zf;

#pragma unroll
    for (int ks = 0; ks < 2; ++ks) {
      fp16x8 afh[4], afl[4], bfh[4], bfl[4];
#pragma unroll
      for (int t = 0; t < 4; ++t) {
        afh[t] = *(const fp16x8*)&M.ks.Khh[t * 16 + l16][ks * 32 + quad * 8];
        afl[t] = *(const fp16x8*)&M.ks.Khl[t * 16 + l16][ks * 32 + quad * 8];
        const size_t po = (size_t)(wn0 + t * 16 + l16) * 64 + ks * 32 + quad * 8;
        bfh[t] = *(const fp16x8*)(phh + po);
        bfl[t] = *(const fp16x8*)(phl + po);
      }
#pragma unroll
      for (int mt = 0; mt < 4; ++mt)
#pragma unroll
        for (int nt = 0; nt < 4; ++nt) {
          acc[mt][nt] = __builtin_amdgcn_mfma_f32_16x16x32_f16(afh[mt], bfh[nt], acc[mt][nt], 0, 0, 0);
          acc[mt][nt] = __builtin_amdgcn_mfma_f32_16x16x32_f16(afh[mt], bfl[nt], acc[mt][nt], 0, 0, 0);
          acc[mt][nt] = __builtin_amdgcn_mfma_f32_16x16x32_f16(afl[mt], bfh[nt], acc[mt][nt], 0, 0, 0);
        }
    }

    float mx = -3.4e38f;
#pragma unroll
    for (int mt = 0; mt < 4; ++mt)
#pragma unroll
      for (int nt = 0; nt < 4; ++nt)
#pragma unroll
        for (int r = 0; r < 4; ++r) mx = fmaxf(mx, acc[mt][nt][r]);
#pragma unroll
    for (int off = 32; off; off >>= 1) mx = fmaxf(mx, __shfl_xor(mx, off));
    if (lane == 0) M.ks.wred[wid] = mx;
    __syncthreads();
    if (tid == 0)
      stabp[bid] = fmaxf(fmaxf(M.ks.wred[0], M.ks.wred[1]), fmaxf(M.ks.wred[2], M.ks.wred[3]));
  }
}

/* ---------------- reduce per-block maxima -> scalar stab ------------------- */
__global__ __launch_bounds__(256) void stab_reduce(
    const float* __restrict__ stabp, float* __restrict__ stab_f)
{
  __shared__ float wred[4];
  const int tid = threadIdx.x;
  float m = -3.4e38f;
  for (int i = tid; i < KSTAB_BLOCKS; i += 256) m = fmaxf(m, stabp[i]);
#pragma unroll
  for (int off = 32; off; off >>= 1) m = fmaxf(m, __shfl_xor(m, off));
  if ((tid & 63) == 0) wred[tid >> 6] = m;
  __syncthreads();
  if (tid == 0)
    *stab_f = fmaxf(fmaxf(wred[0], wred[1]), fmaxf(wred[2], wred[3]));
}

/* ---------------- FAVOR: context & k_sum partials via MFMA ----------------- */
__global__ __launch_bounds__(256, 2) void favor_ctx_mfma(
    const unsigned short* __restrict__ KhH, const unsigned short* __restrict__ KhL,
    const unsigned short* __restrict__ VhH,
    const unsigned short* __restrict__ phh, const unsigned short* __restrict__ phl,
    const float* __restrict__ stab_f,
    float* __restrict__ ctxp, float* __restrict__ ksump, int split)
{
  __shared__ unsigned short Khh[64][72];
  __shared__ unsigned short Khl[64][72];
  __shared__ unsigned short Vt_h[64][72];   /* [d][n] */
  __shared__ unsigned short kp_s[256][72];  /* [m][n] */
  __shared__ float diag_s[64];

  const int tid = threadIdx.x;
  const int wid = tid >> 6, lane = tid & 63;
  const int quad = lane >> 4, l16 = lane & 15;
  const int sidx = blockIdx.x % split;
  const int bh = blockIdx.x / split;
  const int b = bh >> 3, h = bh & 7;
  const int rows = NN / split, nch = rows / 64;
  const float stab = *stab_f;
  const int wn0 = wid * 64;
  const f32x4 zf = {0.f, 0.f, 0.f, 0.f};

  f32x4 acc2[4][4];
#pragma unroll
  for (int i = 0; i < 4; ++i)
#pragma unroll
    for (int j = 0; j < 4; ++j) acc2[i][j] = zf;
  float ksacc[4] = {0.f, 0.f, 0.f, 0.f};

  for (int c = 0; c < nch; ++c) {
    const int n0 = sidx * rows + c * 64;
    __syncthreads();
    {
      const int r = tid >> 2, s2 = tid & 3;
      const size_t off = ((size_t)(b * NN + n0 + r)) * DMM + h * DH + s2 * 16;
      unsigned short kh[16], kl[16], vv[16];
      *(uint4*)&kh[0] = *(const uint4*)(KhH + off);
      *(uint4*)&kh[8] = *(const uint4*)(KhH + off + 8);
      *(uint4*)&kl[0] = *(const uint4*)(KhL + off);
      *(uint4*)&kl[8] = *(const uint4*)(KhL + off + 8);
      *(uint4*)&vv[0] = *(const uint4*)(VhH + off);
      *(uint4*)&vv[8] = *(const uint4*)(VhH + off + 8);
      float kq = 0.f;
#pragma unroll
      for (int j = 0; j < 16; ++j) {
        float f = h2f(kh[j]) + h2f(kl[j]);
        kq = fmaf(f, f, kq);
        Vt_h[s2 * 16 + j][r] = vv[j];
      }
      *(uint4*)&Khh[r][s2 * 16]     = *(uint4*)&kh[0];
      *(uint4*)&Khh[r][s2 * 16 + 8] = *(uint4*)&kh[8];
      *(uint4*)&Khl[r][s2 * 16]     = *(uint4*)&kl[0];
      *(uint4*)&Khl[r][s2 * 16 + 8] = *(uint4*)&kl[8];
      kq += __shfl_xor(kq, 1);
      kq += __shfl_xor(kq, 2);
      if (s2 == 0) diag_s[r] = 0.5f * NRM2 * kq;
    }
    __syncthreads();

    f32x4 acc[4][4];
#pragma unroll
    for (int i = 0; i < 4; ++i)
#pragma unroll
      for (int j = 0; j < 4; ++j) acc[i][j] = zf;
#pragma unroll
    for (int ks = 0; ks < 2; ++ks) {
      fp16x8 afh[4], afl[4], bfh[4], bfl[4];
#pragma unroll
      for (int t = 0; t < 4; ++t) {
        afh[t] = *(const fp16x8*)&Khh[t * 16 + l16][ks * 32 + quad * 8];
        afl[t] = *(const fp16x8*)&Khl[t * 16 + l16][ks * 32 + quad * 8];
        const size_t po = (size_t)(wn0 + t * 16 + l16) * 64 + ks * 32 + quad * 8;
        bfh[t] = *(const fp16x8*)(phh + po);
        bfl[t] = *(const fp16x8*)(phl + po);
      }
#pragma unroll
      for (int mt = 0; mt < 4; ++mt)
#pragma unroll
        for (int nt = 0; nt < 4; ++nt) {
          acc[mt][nt] = __builtin_amdgcn_mfma_f32_16x16x32_f16(afh[mt], bfh[nt], acc[mt][nt], 0, 0, 0);
          acc[mt][nt] = __builtin_amdgcn_mfma_f32_16x16x32_f16(afh[mt], bfl[nt], acc[mt][nt], 0, 0, 0);
          acc[mt][nt] = __builtin_amdgcn_mfma_f32_16x16x32_f16(afl[mt], bfh[nt], acc[mt][nt], 0, 0, 0);
        }
    }

    float ks_i[4] = {0.f, 0.f, 0.f, 0.f};
#pragma unroll
    for (int mt = 0; mt < 4; ++mt) {
#pragma unroll
      for (int nt = 0; nt < 4; ++nt) {
        float pv[4];
#pragma unroll
        for (int reg = 0; reg < 4; ++reg) {
          const int n = mt * 16 + quad * 4 + reg;
          float p = RATIO * (__expf(acc[mt][nt][reg] - diag_s[n] - stab) + EPSF);
          pv[reg] = p;
          ks_i[nt] += p;
        }
        __half2 h0 = __floats2half2_rn(pv[0], pv[1]);
        __half2 h1 = __floats2half2_rn(pv[2], pv[3]);
        uint2 w;
        w.x = *(unsigned*)&h0;
        w.y = *(unsigned*)&h1;
        *(uint2*)&kp_s[wn0 + nt * 16 + l16][mt * 16 + quad * 4] = w;
      }
    }
#pragma unroll
    for (int nt = 0; nt < 4; ++nt) {
      float s = ks_i[nt];
      s += __shfl_xor(s, 16);
      s += __shfl_xor(s, 32);
      ksacc[nt] += s;
    }
    __syncthreads();

#pragma unroll
    for (int ks2 = 0; ks2 < 2; ++ks2) {
      fp16x8 ap[4], bv[4];
#pragma unroll
      for (int t = 0; t < 4; ++t) {
        ap[t] = *(const fp16x8*)&kp_s[wn0 + t * 16 + l16][ks2 * 32 + quad * 8];
        bv[t] = *(const fp16x8*)&Vt_h[t * 16 + l16][ks2 * 32 + quad * 8];
      }
#pragma unroll
      for (int mt = 0; mt < 4; ++mt)
#pragma unroll
        for (int nt = 0; nt < 4; ++nt)
          acc2[mt][nt] = __builtin_amdgcn_mfma_f32_16x16x32_f16(ap[mt], bv[nt], acc2[mt][nt], 0, 0, 0);
    }
  }

  {
    float* dst = ctxp + ((size_t)(bh * split + sidx)) * MM * DH;
#pragma unroll
    for (int mt = 0; mt < 4; ++mt)
#pragma unroll
      for (int nt = 0; nt < 4; ++nt) {
        const int m = wn0 + mt * 16 + quad * 4;
        const int d = nt * 16 + l16;
        *(f32x4*)(dst + (size_t)d * MM + m) = acc2[mt][nt];
      }
    if (quad == 0) {
      float* kd = ksump + (size_t)(bh * split + sidx) * MM;
#pragma unroll
      for (int nt = 0; nt < 4; ++nt) kd[wn0 + nt * 16 + l16] = ksacc[nt];
    }
  }
}

/* ---------------- FAVOR: reduce partials -> ctxT fp16 [bh][d][m] + ksum ---- */
__global__ __launch_bounds__(256) void favor_reduce(
    const float* __restrict__ ctxp, const float* __restrict__ ksump,
    unsigned short* __restrict__ ctxT_h, float* __restrict__ ksum, int split)
{
  int i = blockIdx.x * 256 + threadIdx.x;
  if (i < BB * GHH * MM * DH) {
    int bh = i / (MM * DH);
    int md = i % (MM * DH);
    float s = 0.f;
    for (int k = 0; k < split; ++k) s += ctxp[((size_t)(bh * split + k)) * MM * DH + md];
    ctxT_h[i] = f2h(s);
  }
  if (i < BB * GHH * MM) {
    int bh = i / MM, m = i % MM;
    float s = 0.f;
    for (int k = 0; k < split; ++k) s += ksump[(bh * split + k) * MM + m];
    ksum[i] = s;
  }
}

/* ---------------- FAVOR fused output via MFMA (LDS-union, 4 blocks/CU) ----- */
__global__ __launch_bounds__(256, 4) void favor_out_mfma(
    const unsigned short* __restrict__ QhH, const unsigned short* __restrict__ QhL,
    const unsigned short* __restrict__ phh, const unsigned short* __restrict__ phl,
    const unsigned short* __restrict__ ctxT_h, const float* __restrict__ ksum,
    unsigned short* __restrict__ xH, unsigned short* __restrict__ xL)
{
  __shared__ union {
    struct { unsigned short Qhh[64][72]; unsigned short Qhl[64][72]; } a;
    unsigned short qp[64][264];
  } sm;
  __shared__ float red[4][64];
  __shared__ float dred[4][64];
  __shared__ float diag4[64][4];
  __shared__ float diag_s[64];
  __shared__ float dinv_s[64];
  __shared__ float ksum_s[256];

  const int tid = threadIdx.x;
  const int wid = tid >> 6, lane = tid & 63;
  const int quad = lane >> 4, l16 = lane & 15;
  const int bh = blockIdx.x >> 6;
  const int chunk = blockIdx.x & 63;
  const int b = bh >> 3, h = bh & 7;
  const int n0 = chunk * 64;
  const f32x4 zf = {0.f, 0.f, 0.f, 0.f};

  /* load Q chunk from planes; diag partials from hi+lo */
  {
    const int r = tid >> 2, s2 = tid & 3;
    const size_t off = ((size_t)(b * NN + n0 + r)) * DMM + h * DH + s2 * 16;
    unsigned short qh[16], ql[16];
    *(uint4*)&qh[0] = *(const uint4*)(QhH + off);
    *(uint4*)&qh[8] = *(const uint4*)(QhH + off + 8);
    *(uint4*)&ql[0] = *(const uint4*)(QhL + off);
    *(uint4*)&ql[8] = *(const uint4*)(QhL + off + 8);
    float sq = 0.f;
#pragma unroll
    for (int j = 0; j < 16; ++j) {
      float f = h2f(qh[j]) + h2f(ql[j]);
      sq = fmaf(f, f, sq);
    }
    diag4[r][s2] = sq;
    *(uint4*)&sm.a.Qhh[r][s2 * 16]     = *(uint4*)&qh[0];
    *(uint4*)&sm.a.Qhh[r][s2 * 16 + 8] = *(uint4*)&qh[8];
    *(uint4*)&sm.a.Qhl[r][s2 * 16]     = *(uint4*)&ql[0];
    *(uint4*)&sm.a.Qhl[r][s2 * 16 + 8] = *(uint4*)&ql[8];
    ksum_s[tid] = ksum[bh * MM + tid];
  }
  __syncthreads();
  if (tid < 64)
    diag_s[tid] = 0.5f * NRM2 * (diag4[tid][0] + diag4[tid][1] + diag4[tid][2] + diag4[tid][3]);

  /* dd GEMM: rows 64 x wave's 64 feature-cols, K=64, split-fp16 (hh+hl+lh) */
  const int wn0 = wid * 64;
  f32x4 acc[4][4];
#pragma unroll
  for (int i = 0; i < 4; ++i)
#pragma unroll
    for (int j = 0; j < 4; ++j) acc[i][j] = zf;

#pragma unroll
  for (int ks = 0; ks < 2; ++ks) {
    fp16x8 afh[4], afl[4], bfh[4], bfl[4];
#pragma unroll
    for (int t = 0; t < 4; ++t) {
      afh[t] = *(const fp16x8*)&sm.a.Qhh[t * 16 + l16][ks * 32 + quad * 8];
      afl[t] = *(const fp16x8*)&sm.a.Qhl[t * 16 + l16][ks * 32 + quad * 8];
      const size_t po = (size_t)(wn0 + t * 16 + l16) * 64 + ks * 32 + quad * 8;
      bfh[t] = *(const fp16x8*)(phh + po);
      bfl[t] = *(const fp16x8*)(phl + po);
    }
#pragma unroll
    for (int mt = 0; mt < 4; ++mt)
#pragma unroll
      for (int nt = 0; nt < 4; ++nt) {
        acc[mt][nt] = __builtin_amdgcn_mfma_f32_16x16x32_f16(afh[mt], bfh[nt], acc[mt][nt], 0, 0, 0);
        acc[mt][nt] = __builtin_amdgcn_mfma_f32_16x16x32_f16(afh[mt], bfl[nt], acc[mt][nt], 0, 0, 0);
        acc[mt][nt] = __builtin_amdgcn_mfma_f32_16x16x32_f16(afl[mt], bfh[nt], acc[mt][nt], 0, 0, 0);
      }
  }

  /* per-row wave-local max -> LDS */
#pragma unroll
  for (int mt = 0; mt < 4; ++mt)
#pragma unroll
    for (int reg = 0; reg < 4; ++reg) {
      float v = fmaxf(fmaxf(acc[mt][0][reg], acc[mt][1][reg]),
                      fmaxf(acc[mt][2][reg], acc[mt][3][reg]));
      v = fmaxf(v, __shfl_xor(v, 1));
      v = fmaxf(v, __shfl_xor(v, 2));
      v = fmaxf(v, __shfl_xor(v, 4));
      v = fmaxf(v, __shfl_xor(v, 8));
      if (l16 == 0) red[wid][mt * 16 + quad * 4 + reg] = v;
    }
  __syncthreads();   /* all Qhh/Qhl reads drained -> qp aliasing safe */

  /* qp = RATIO*(exp(dd - diag - stab) + EPS); dsum partials; qp -> fp16 LDS */
  float ksv[4];
#pragma unroll
  for (int nt = 0; nt < 4; ++nt) ksv[nt] = ksum_s[wn0 + nt * 16 + l16];
#pragma unroll
  for (int mt = 0; mt < 4; ++mt)
#pragma unroll
    for (int reg = 0; reg < 4; ++reg) {
      const int row = mt * 16 + quad * 4 + reg;
      float stab = fmaxf(fmaxf(red[0][row], red[1][row]),
                         fmaxf(red[2][row], red[3][row]));
      float base = diag_s[row] + stab;
      float dsum = 0.f;
#pragma unroll
      for (int nt = 0; nt < 4; ++nt) {
        float p = RATIO * (__expf(acc[mt][nt][reg] - base) + EPSF);
        acc[mt][nt][reg] = p;
        dsum = fmaf(p, ksv[nt], dsum);
      }
      dsum += __shfl_xor(dsum, 1);
      dsum += __shfl_xor(dsum, 2);
      dsum += __shfl_xor(dsum, 4);
      dsum += __shfl_xor(dsum, 8);
      if (l16 == 0) dred[wid][row] = dsum;
#pragma unroll
      for (int nt = 0; nt < 4; ++nt)
        sm.qp[row][wn0 + nt * 16 + l16] = f2h(acc[mt][nt][reg]);
    }
  __syncthreads();
  if (tid < 64)
    dinv_s[tid] = 1.0f / (dred[0][tid] + dred[1][tid] + dred[2][tid] + dred[3][tid]);

  /* PV: out[64 x wave's 16 d-cols] = qp[64x256] @ ctxT rows, K=256 */
  const int wn2 = wid * 16;
  f32x4 acc2[4];
#pragma unroll
  for (int mt = 0; mt < 4; ++mt) acc2[mt] = zf;
#pragma unroll
  for (int ksp = 0; ksp < 8; ++ksp) {
    fp16x8 bv = *(const fp16x8*)(ctxT_h + ((size_t)bh * DH + wn2 + l16) * MM + ksp * 32 + quad * 8);
    fp16x8 ap[4];
#pragma unroll
    for (int mt = 0; mt < 4; ++mt)
      ap[mt] = *(const fp16x8*)&sm.qp[mt * 16 + l16][ksp * 32 + quad * 8];
#pragma unroll
    for (int mt = 0; mt < 4; ++mt)
      acc2[mt] = __builtin_amdgcn_mfma_f32_16x16x32_f16(ap[mt], bv, acc2[mt], 0, 0, 0);
  }
  __syncthreads();

  /* epilogue: scale by 1/dsum, split-fp16 into xH/xL */
#pragma unroll
  for (int mt = 0; mt < 4; ++mt)
#pragma unroll
    for (int reg = 0; reg < 4; ++reg) {
      const int row = mt * 16 + quad * 4 + reg;
      float o = acc2[mt][reg] * dinv_s[row];
      const size_t base = ((size_t)(b * NN + n0 + row)) * DMM + h * DH + wn2 + l16;
      unsigned short hi = f2h(o);
      xH[base] = hi;
      xL[base] = f2h(o - h2f(hi));
    }
}

/* ---------------- local attention via f16 MFMA (flash-style) --------------- */
__global__ __launch_bounds__(256) void local_attn2(
    const unsigned short* __restrict__ Qlh, const unsigned short* __restrict__ Klh,
    const unsigned short* __restrict__ Vt,
    unsigned short* __restrict__ xH, unsigned short* __restrict__ xL)
{
  __shared__ unsigned short Pl[4][32][72];
  const int w = blockIdx.x, h = blockIdx.y, b = blockIdx.z;
  const int tid = threadIdx.x;
  const int wid = tid >> 6, lane = tid & 63;
  const int quad = lane >> 4, l16 = lane & 15;
  const int bh = b * LHH + h;
  const int qn0 = w * WW + wid * 32;

  fp16x8 Aq[2][2];
#pragma unroll
  for (int mt = 0; mt < 2; ++mt)
#pragma unroll
    for (int ks = 0; ks < 2; ++ks)
      Aq[mt][ks] = *(const fp16x8*)(Qlh + ((size_t)bh * NN + qn0 + mt * 16 + l16) * 64 + ks * 32 + quad * 8);

  float m_run[8], l_run[8];
  f32x4 Oacc[2][4];
  const f32x4 zf = {0.f, 0.f, 0.f, 0.f};
#pragma unroll
  for (int r = 0; r < 8; ++r) { m_run[r] = -3.4e38f; l_run[r] = 0.f; }
#pragma unroll
  for (int mt = 0; mt < 2; ++mt)
#pragma unroll
    for (int nt = 0; nt < 4; ++nt) Oacc[mt][nt] = zf;

  const int wb_lo = (w == 0) ? 0 : w - 1;
  const int wb_hi = (w == NWIN - 1) ? w : w + 1;
  for (int wb = wb_lo; wb <= wb_hi; ++wb) {
    for (int half = 0; half < 2; ++half) {
      const int kn0 = wb * WW + half * 64;
      f32x4 sacc[2][4];
#pragma unroll
      for (int mt = 0; mt < 2; ++mt)
#pragma unroll
        for (int nt = 0; nt < 4; ++nt) sacc[mt][nt] = zf;

#pragma unroll
      for (int ks = 0; ks < 2; ++ks) {
        fp16x8 Bk[4];
#pragma unroll
        for (int nt = 0; nt < 4; ++nt)
          Bk[nt] = *(const fp16x8*)(Klh + ((size_t)bh * NN + kn0 + nt * 16 + l16) * 64 + ks * 32 + quad * 8);
#pragma unroll
        for (int mt = 0; mt < 2; ++mt)
#pragma unroll
          for (int nt = 0; nt < 4; ++nt)
            sacc[mt][nt] = __builtin_amdgcn_mfma_f32_16x16x32_f16(Aq[mt][ks], Bk[nt], sacc[mt][nt], 0, 0, 0);
      }

      /* online softmax per row (row = mt*16 + quad*4 + reg) */
#pragma unroll
      for (int mt = 0; mt < 2; ++mt) {
#pragma unroll
        for (int reg = 0; reg < 4; ++reg) {
          const int r8 = mt * 4 + reg;
          float v = fmaxf(fmaxf(sacc[mt][0][reg], sacc[mt][1][reg]),
                          fmaxf(sacc[mt][2][reg], sacc[mt][3][reg]));
          v = fmaxf(v, __shfl_xor(v, 1));
          v = fmaxf(v, __shfl_xor(v, 2));
          v = fmaxf(v, __shfl_xor(v, 4));
          v = fmaxf(v, __shfl_xor(v, 8));
          float mnew = fmaxf(m_run[r8], v);
          float alpha = __expf(m_run[r8] - mnew);
          m_run[r8] = mnew;
          float ps = 0.f;
#pragma unroll
          for (int nt = 0; nt < 4; ++nt) {
            float p = __expf(sacc[mt][nt][reg] - mnew);
            sacc[mt][nt][reg] = p;
            ps += p;
          }
          ps += __shfl_xor(ps, 1);
          ps += __shfl_xor(ps, 2);
          ps += __shfl_xor(ps, 4);
          ps += __shfl_xor(ps, 8);
          l_run[r8] = l_run[r8] * alpha + ps;
#pragma unroll
          for (int nt = 0; nt < 4; ++nt) Oacc[mt][nt][reg] *= alpha;
        }
      }

      /* write P fp16 (C-layout -> [qrow][key] in LDS, wave-local) */
#pragma unroll
      for (int mt = 0; mt < 2; ++mt)
#pragma unroll
        for (int nt = 0; nt < 4; ++nt)
#pragma unroll
          for (int reg = 0; reg < 4; ++reg)
            Pl[wid][mt * 16 + quad * 4 + reg][nt * 16 + l16] = f2h(sacc[mt][nt][reg]);

      /* PV */
#pragma unroll
      for (int kstep = 0; kstep < 2; ++kstep) {
        fp16x8 Ap[2];
#pragma unroll
        for (int mt = 0; mt < 2; ++mt)
          Ap[mt] = *(const fp16x8*)&Pl[wid][mt * 16 + l16][kstep * 32 + quad * 8];
        fp16x8 Bv[4];
#pragma unroll
        for (int nt = 0; nt < 4; ++nt)
          Bv[nt] = *(const fp16x8*)(Vt + ((size_t)bh * DH + nt * 16 + l16) * NN + kn0 + kstep * 32 + quad * 8);
#pragma unroll
        for (int mt = 0; mt < 2; ++mt)
#pragma unroll
          for (int nt = 0; nt < 4; ++nt)
            Oacc[mt][nt] = __builtin_amdgcn_mfma_f32_16x16x32_f16(Ap[mt], Bv[nt], Oacc[mt][nt], 0, 0, 0);
      }
    }
  }

  /* epilogue: divide by l, split-fp16 into xH/xL local-head columns */
#pragma unroll
  for (int mt = 0; mt < 2; ++mt)
#pragma unroll
    for (int reg = 0; reg < 4; ++reg) {
      const float inv = 1.0f / l_run[mt * 4 + reg];
      const int n = qn0 + mt * 16 + quad * 4 + reg;
      const size_t base = ((size_t)(b * NN + n)) * DMM + GHH * DH + h * DH;
#pragma unroll
      for (int nt = 0; nt < 4; ++nt) {
        float o = Oacc[mt][nt][reg] * inv;
        unsigned short hi = f2h(o);
        xH[base + nt * 16 + l16] = hi;
        xL[base + nt * 16 + l16] = f2h(o - h2f(hi));
      }
    }
}

/* ---------------- launcher -------------------------------------------------- */
extern "C" void kernel_launch(void* const* d_in, const int* in_sizes, int n_in,
                              void* d_out, int out_size, void* d_ws, size_t ws_size,
                              hipStream_t stream)
{
  (void)in_sizes; (void)n_in; (void)out_size;
  const float* x    = (const float*)d_in[0];
  const float* Wq   = (const float*)d_in[2];
  const float* Wk   = (const float*)d_in[3];
  const float* Wv   = (const float*)d_in[4];
  const float* Wo   = (const float*)d_in[5];
  const float* bo   = (const float*)d_in[6];
  const float* proj = (const float*)d_in[7];
  float* out = (float*)d_out;

  const size_t WSZ = (size_t)DMM * DMM;
  const size_t XSP = (size_t)BB * NN * DMM;
  const size_t wbuf_f = (4 * WSZ * 2 + 3) / 4;
  const size_t LSZ = (size_t)BB * LHH * NN * DH;
  const size_t lbuf_f = (3 * LSZ * 2 + 3) / 4;
  const size_t fixed_f = (size_t)3 * XSP + (size_t)BB * GHH * MM * DH
                       + (size_t)BB * GHH * MM + KSTAB_BLOCKS + 16 + MM * DH + 16
                       + wbuf_f + 16 + lbuf_f + 16;

  int split = 8;
  for (int s = 32; s >= 8; s >>= 1) {
    size_t part = (size_t)BB * GHH * s * (MM * DH + MM);
    size_t region = part > XSP ? part : XSP;
    if ((fixed_f + region) * 4 <= ws_size) { split = s; break; }
  }
  size_t part_f = (size_t)BB * GHH * split * (MM * DH + MM);
  size_t region_f = XSP > part_f ? XSP : part_f;

  unsigned short* QhH = (unsigned short*)d_ws;
  unsigned short* QhL = QhH + XSP;
  unsigned short* KhH = QhH + 2 * XSP;
  unsigned short* KhL = QhH + 3 * XSP;
  unsigned short* VhH = QhH + 4 * XSP;
  float* region = (float*)d_ws + 3 * XSP;
  float* ctxp  = region;
  float* ksump = ctxp + (size_t)BB * GHH * split * MM * DH;
  unsigned short* xH = (unsigned short*)region;
  unsigned short* xL = xH + XSP;
  float* ctx   = region + region_f;
  unsigned short* ctxT_h = (unsigned short*)ctx;
  float* ksum  = ctx + (size_t)BB * GHH * MM * DH;
  float* stabp = ksum + BB * GHH * MM;
  float* stab_f = stabp + KSTAB_BLOCKS;
  unsigned short* proj_hh = (unsigned short*)(stab_f + 16);
  unsigned short* proj_hl = proj_hh + MM * DH;
  unsigned short* wsp = proj_hl + MM * DH;
  unsigned short* WqH = wsp;
  unsigned short* WkH = wsp + WSZ;
  unsigned short* WvH = wsp + 2 * WSZ;
  unsigned short* WoH = wsp + 3 * WSZ;
  unsigned short* Qlh = wsp + 4 * WSZ;
  unsigned short* Klh = Qlh + LSZ;
  unsigned short* Vtl = Klh + LSZ;

  dim3 blk(256);
  dim3 mg(DMM / 128, (BB * NN) / 128);
  const int PREP_BLOCKS = 4 * WGRID + AGRID + 64;
  const int MID_BLOCKS  = 256 + 1024 + KSTAB_BLOCKS;

  prep_all<<<PREP_BLOCKS, blk, 0, stream>>>(Wq, Wk, Wv, Wo, x, proj,
                                            WqH, WkH, WvH, WoH, xH, xL,
                                            proj_hh, proj_hl);
  gemm_mfma_sp<<<mg, blk, 0, stream>>>(xH, xL, WqH, QhH, QhL, DMM, DMM);
  gemm_mfma_sp<<<mg, blk, 0, stream>>>(xH, xL, WkH, KhH, KhL, DMM, DMM);
  gemm_mfma_sp<<<mg, blk, 0, stream>>>(xH, xL, WvH, VhH, (unsigned short*)0, DMM, DMM);
  mid_all<<<MID_BLOCKS, blk, 0, stream>>>(QhH, KhH, KhL, VhH, proj_hh, proj_hl,
                                          Qlh, Klh, Vtl, stabp);
  stab_reduce<<<1, blk, 0, stream>>>(stabp, stab_f);
  favor_ctx_mfma<<<BB * GHH * split, blk, 0, stream>>>(KhH, KhL, VhH, proj_hh, proj_hl,
                                                       stab_f, ctxp, ksump, split);
  favor_reduce<<<(BB * GHH * MM * DH) / 256, blk, 0, stream>>>(ctxp, ksump, ctxT_h, ksum, split);
  favor_out_mfma<<<BB * GHH * (NN / 64), blk, 0, stream>>>(QhH, QhL, proj_hh, proj_hl,
                                                           ctxT_h, ksum, xH, xL);
  local_attn2<<<dim3(NWIN, LHH, BB), blk, 0, stream>>>(Qlh, Klh, Vtl, xH, xL);
  gemm_mfma_pre<<<mg, blk, 0, stream>>>(xH, xL, WoH, bo, out, DMM, DMM);
}

// Round 13
// 497.297 us; speedup vs baseline: 1.1502x; 1.0113x over previous
//
#include <hip/hip_runtime.h>
#include <hip/hip_fp16.h>
#include <math.h>

#define BB 4
#define NN 4096
#define DMM 768
#define HHH 12
#define LHH 4
#define GHH 8
#define DH 64
#define MM 256
#define WW 128
#define NWIN (NN/WW)
#define EPSF 1.0e-4f
#define NRM 0.35355339059327373f   /* 64^-0.25 */
#define NRM2 0.125f                /* 64^-0.5 = NRM^2 */
#define RATIO 0.0625f              /* 256^-0.5 */
#define LN1E4_32 0.28782313662425572f  /* ln(10000)/32 */
#define KSTAB_BLOCKS (BB * GHH * (NN / 64))
#define WGRID ((DMM*DMM)/256)
#define AGRID ((BB*NN*DMM)/1024)

using fp16x8 = __attribute__((ext_vector_type(8))) _Float16;
using f32x4  = __attribute__((ext_vector_type(4))) float;

static __device__ __forceinline__ unsigned short f2h(float x) {
  return __half_as_ushort(__float2half(x));
}
static __device__ __forceinline__ float h2f(unsigned short u) {
  union { unsigned short s; _Float16 f; } cv; cv.s = u;
  return (float)cv.f;
}
/* direct global->LDS 16B DMA (linear LDS dest: wave-uniform base + lane*16) */
static __device__ __forceinline__ void gload16(const unsigned short* g, unsigned short* l) {
  __builtin_amdgcn_global_load_lds(
      (const __attribute__((address_space(1))) void*)g,
      (__attribute__((address_space(3))) void*)l, 16, 0, 0);
}

/* ------- prep fat kernel: w_split x4 | a_split | transpose_proj ------------ */
__global__ __launch_bounds__(256) void prep_all(
    const float* __restrict__ Wq, const float* __restrict__ Wk,
    const float* __restrict__ Wv, const float* __restrict__ Wo,
    const float* __restrict__ x, const float* __restrict__ proj,
    unsigned short* __restrict__ WqH, unsigned short* __restrict__ WkH,
    unsigned short* __restrict__ WvH, unsigned short* __restrict__ WoH,
    unsigned short* __restrict__ xH, unsigned short* __restrict__ xL,
    unsigned short* __restrict__ phh, unsigned short* __restrict__ phl)
{
  int bid = blockIdx.x;
  if (bid < 4 * WGRID) {                       /* w_split: transpose + fp16 */
    const float* W = (bid < WGRID) ? Wq : (bid < 2 * WGRID) ? Wk
                   : (bid < 3 * WGRID) ? Wv : Wo;
    unsigned short* Wh = (bid < WGRID) ? WqH : (bid < 2 * WGRID) ? WkH
                       : (bid < 3 * WGRID) ? WvH : WoH;
    int o = (bid % WGRID) * 256 + threadIdx.x;
    int k = o / DMM, n = o % DMM;
    Wh[(size_t)n * DMM + k] = f2h(W[o]);
    return;
  }
  bid -= 4 * WGRID;
  if (bid < AGRID) {                           /* a_split */
    size_t o = ((size_t)bid * 256 + threadIdx.x) * 4;
    float4 v = *(const float4*)(x + o);
    float f[4] = {v.x, v.y, v.z, v.w};
    unsigned short hi[4], lo[4];
#pragma unroll
    for (int i = 0; i < 4; ++i) {
      hi[i] = f2h(f[i]);
      lo[i] = f2h(f[i] - h2f(hi[i]));
    }
    *(uint2*)(xH + o) = *(uint2*)&hi[0];
    *(uint2*)(xL + o) = *(uint2*)&lo[0];
    return;
  }
  bid -= AGRID;
  {                                            /* transpose_proj (64 blocks) */
    int o = bid * 256 + threadIdx.x;
    int k = o >> 8, m = o & 255;
    float v = proj[m * 64 + k] * NRM;
    unsigned short hh = f2h(v);
    phh[m * 64 + k] = hh;
    phl[m * 64 + k] = f2h(v - h2f(hh));
  }
}

/* ------- split-fp16 MFMA GEMM -> fp32 C (+bias); out-projection ----------- */
__global__ __launch_bounds__(256) void gemm_mfma_pre(
    const unsigned short* __restrict__ Ahi, const unsigned short* __restrict__ Alo,
    const unsigned short* __restrict__ Bhi,
    const float* __restrict__ bias, float* __restrict__ C, int K, int Nc)
{
  __shared__ unsigned short Ah[128][32];
  __shared__ unsigned short Al[128][32];
  __shared__ unsigned short Bh[128][32];

  const int tid = threadIdx.x;
  const int wid = tid >> 6, lane = tid & 63;
  const int quad = lane >> 4, l16 = lane & 15;

  const int nwg = gridDim.x * gridDim.y;
  int hw = blockIdx.y * gridDim.x + blockIdx.x;
  int logical = ((nwg & 7) == 0) ? ((hw & 7) * (nwg >> 3) + (hw >> 3)) : hw;
  const int col0 = (logical % gridDim.x) * 128;
  const int row0 = (logical / gridDim.x) * 128;

  const int wm = (wid & 1) * 64, wn = (wid >> 1) * 64;
  const int sw8 = (quad ^ ((l16 >> 1) & 3)) * 8;

  const int rr = tid >> 2;
  const int cg8 = ((tid & 3) ^ ((tid >> 3) & 3)) * 8;

  f32x4 acc[4][4];
  const f32x4 zf = {0.f, 0.f, 0.f, 0.f};
#pragma unroll
  for (int i = 0; i < 4; ++i)
#pragma unroll
    for (int j = 0; j < 4; ++j) acc[i][j] = zf;

  for (int k0 = 0; k0 < K; k0 += 32) {
    __syncthreads();
    {
      const size_t ro0 = (size_t)(row0 + rr) * K + k0 + cg8;
      const size_t ro1 = (size_t)(row0 + 64 + rr) * K + k0 + cg8;
      const size_t co0 = (size_t)(col0 + rr) * K + k0 + cg8;
      const size_t co1 = (size_t)(col0 + 64 + rr) * K + k0 + cg8;
      unsigned short* la  = &Ah[0][0] + tid * 8;
      unsigned short* lal = &Al[0][0] + tid * 8;
      unsigned short* lb  = &Bh[0][0] + tid * 8;
      gload16(Ahi + ro0, la);
      gload16(Ahi + ro1, la + 2048);
      gload16(Alo + ro0, lal);
      gload16(Alo + ro1, lal + 2048);
      gload16(Bhi + co0, lb);
      gload16(Bhi + co1, lb + 2048);
    }
    __syncthreads();

    fp16x8 afh[4], afl[4], bfh[4];
#pragma unroll
    for (int t = 0; t < 4; ++t) {
      afh[t] = *(const fp16x8*)&Ah[wm + t * 16 + l16][sw8];
      afl[t] = *(const fp16x8*)&Al[wm + t * 16 + l16][sw8];
      bfh[t] = *(const fp16x8*)&Bh[wn + t * 16 + l16][sw8];
    }
#pragma unroll
    for (int ti = 0; ti < 4; ++ti)
#pragma unroll
      for (int tj = 0; tj < 4; ++tj) {
        acc[ti][tj] = __builtin_amdgcn_mfma_f32_16x16x32_f16(afh[ti], bfh[tj], acc[ti][tj], 0, 0, 0);
        acc[ti][tj] = __builtin_amdgcn_mfma_f32_16x16x32_f16(afl[ti], bfh[tj], acc[ti][tj], 0, 0, 0);
      }
  }

  float bv[4] = {0.f, 0.f, 0.f, 0.f};
  if (bias) {
#pragma unroll
    for (int tj = 0; tj < 4; ++tj) bv[tj] = bias[col0 + wn + tj * 16 + l16];
  }
#pragma unroll
  for (int ti = 0; ti < 4; ++ti) {
    const int gr = row0 + wm + ti * 16 + quad * 4;
#pragma unroll
    for (int tj = 0; tj < 4; ++tj) {
      const int gc = col0 + wn + tj * 16 + l16;
      float* cp = C + (size_t)gr * Nc + gc;
#pragma unroll
      for (int r = 0; r < 4; ++r)
        cp[(size_t)r * Nc] = acc[ti][tj][r] + bv[tj];
    }
  }
}

/* ------- split-fp16 MFMA GEMM -> split-fp16 C planes (QKV path) ------------ */
__global__ __launch_bounds__(256) void gemm_mfma_sp(
    const unsigned short* __restrict__ Ahi, const unsigned short* __restrict__ Alo,
    const unsigned short* __restrict__ Bhi,
    unsigned short* __restrict__ Chi, unsigned short* __restrict__ Clo,
    int K, int Nc)
{
  __shared__ unsigned short Ah[128][32];
  __shared__ unsigned short Al[128][32];
  __shared__ unsigned short Bh[128][32];

  const int tid = threadIdx.x;
  const int wid = tid >> 6, lane = tid & 63;
  const int quad = lane >> 4, l16 = lane & 15;

  const int nwg = gridDim.x * gridDim.y;
  int hw = blockIdx.y * gridDim.x + blockIdx.x;
  int logical = ((nwg & 7) == 0) ? ((hw & 7) * (nwg >> 3) + (hw >> 3)) : hw;
  const int col0 = (logical % gridDim.x) * 128;
  const int row0 = (logical / gridDim.x) * 128;

  const int wm = (wid & 1) * 64, wn = (wid >> 1) * 64;
  const int sw8 = (quad ^ ((l16 >> 1) & 3)) * 8;

  const int rr = tid >> 2;
  const int cg8 = ((tid & 3) ^ ((tid >> 3) & 3)) * 8;

  f32x4 acc[4][4];
  const f32x4 zf = {0.f, 0.f, 0.f, 0.f};
#pragma unroll
  for (int i = 0; i < 4; ++i)
#pragma unroll
    for (int j = 0; j < 4; ++j) acc[i][j] = zf;

  for (int k0 = 0; k0 < K; k0 += 32) {
    __syncthreads();
    {
      const size_t ro0 = (size_t)(row0 + rr) * K + k0 + cg8;
      const size_t ro1 = (size_t)(row0 + 64 + rr) * K + k0 + cg8;
      const size_t co0 = (size_t)(col0 + rr) * K + k0 + cg8;
      const size_t co1 = (size_t)(col0 + 64 + rr) * K + k0 + cg8;
      unsigned short* la  = &Ah[0][0] + tid * 8;
      unsigned short* lal = &Al[0][0] + tid * 8;
      unsigned short* lb  = &Bh[0][0] + tid * 8;
      gload16(Ahi + ro0, la);
      gload16(Ahi + ro1, la + 2048);
      gload16(Alo + ro0, lal);
      gload16(Alo + ro1, lal + 2048);
      gload16(Bhi + co0, lb);
      gload16(Bhi + co1, lb + 2048);
    }
    __syncthreads();

    fp16x8 afh[4], afl[4], bfh[4];
#pragma unroll
    for (int t = 0; t < 4; ++t) {
      afh[t] = *(const fp16x8*)&Ah[wm + t * 16 + l16][sw8];
      afl[t] = *(const fp16x8*)&Al[wm + t * 16 + l16][sw8];
      bfh[t] = *(const fp16x8*)&Bh[wn + t * 16 + l16][sw8];
    }
#pragma unroll
    for (int ti = 0; ti < 4; ++ti)
#pragma unroll
      for (int tj = 0; tj < 4; ++tj) {
        acc[ti][tj] = __builtin_amdgcn_mfma_f32_16x16x32_f16(afh[ti], bfh[tj], acc[ti][tj], 0, 0, 0);
        acc[ti][tj] = __builtin_amdgcn_mfma_f32_16x16x32_f16(afl[ti], bfh[tj], acc[ti][tj], 0, 0, 0);
      }
  }

#pragma unroll
  for (int ti = 0; ti < 4; ++ti) {
    const int gr = row0 + wm + ti * 16 + quad * 4;
#pragma unroll
    for (int tj = 0; tj < 4; ++tj) {
      const int gc = col0 + wn + tj * 16 + l16;
#pragma unroll
      for (int r = 0; r < 4; ++r) {
        float c = acc[ti][tj][r];
        unsigned short hi = f2h(c);
        Chi[(size_t)(gr + r) * Nc + gc] = hi;
        if (Clo) Clo[(size_t)(gr + r) * Nc + gc] = f2h(c - h2f(hi));
      }
    }
  }
}

/* ------- mid fat kernel: rot_qk (low-VGPR chunked) | v_trans | kstab ------- */
__global__ __launch_bounds__(256, 4) void mid_all(
    const unsigned short* __restrict__ QhH, const unsigned short* __restrict__ KhH,
    const unsigned short* __restrict__ KhL, const unsigned short* __restrict__ VhH,
    const unsigned short* __restrict__ phh, const unsigned short* __restrict__ phl,
    unsigned short* __restrict__ Qlh, unsigned short* __restrict__ Klh,
    unsigned short* __restrict__ Vtl, float* __restrict__ stabp)
{
  __shared__ union {
    unsigned short T[64][72];
    struct { unsigned short Khh[64][72]; unsigned short Khl[64][72]; float wred[4]; } ks;
  } M;

  const int tid = threadIdx.x;
  int bid = blockIdx.x;

  if (bid < 256) {                             /* rot_qk, chunked (low VGPR) */
    int idx = bid * 256 + tid;
    int n = idx & (NN - 1);
    int bh = idx >> 12;
    int b = bh >> 2, h = bh & 3;
    const unsigned short* qs = QhH + ((size_t)(b * NN + n)) * DMM + GHH * DH + h * DH;
    const unsigned short* ks = KhH + ((size_t)(b * NN + n)) * DMM + GHH * DH + h * DH;
    unsigned short* qd = Qlh + (size_t)idx * 64;
    unsigned short* kd = Klh + (size_t)idx * 64;
#pragma unroll 1
    for (int t = 0; t < 4; ++t) {
      unsigned short q1v[8], q2v[8], k1v[8], k2v[8];
      *(uint4*)&q1v[0] = *(const uint4*)(qs + t * 8);
      *(uint4*)&q2v[0] = *(const uint4*)(qs + t * 8 + 32);
      *(uint4*)&k1v[0] = *(const uint4*)(ks + t * 8);
      *(uint4*)&k2v[0] = *(const uint4*)(ks + t * 8 + 32);
      unsigned short qo1[8], qo2[8], ko1[8], ko2[8];
#pragma unroll
      for (int j = 0; j < 8; ++j) {
        int i = t * 8 + j;
        float invf = __expf((float)i * -LN1E4_32);
        float th = (float)n * invf;
        float s, c;
        sincosf(th, &s, &c);
        float q1 = h2f(q1v[j]), q2 = h2f(q2v[j]);
        float k1 = h2f(k1v[j]), k2 = h2f(k2v[j]);
        qo1[j] = f2h(fmaf(q1, c, -q2 * s) * NRM2);
        qo2[j] = f2h(fmaf(q2, c, q1 * s) * NRM2);
        ko1[j] = f2h(fmaf(k1, c, -k2 * s));
        ko2[j] = f2h(fmaf(k2, c, k1 * s));
      }
      *(uint4*)(qd + t * 8)      = *(uint4*)&qo1[0];
      *(uint4*)(qd + t * 8 + 32) = *(uint4*)&qo2[0];
      *(uint4*)(kd + t * 8)      = *(uint4*)&ko1[0];
      *(uint4*)(kd + t * 8 + 32) = *(uint4*)&ko2[0];
    }
    return;
  }
  bid -= 256;
  if (bid < 1024) {                            /* v_trans */
    const int nb = bid & 63, h = (bid >> 6) & 3, b = bid >> 8;
    const int n0 = nb * 64;
    {
      int r = tid >> 2, g = tid & 3;
      const unsigned short* src = VhH + ((size_t)(b * NN + n0 + r)) * DMM + GHH * DH + h * DH + g * 16;
      unsigned short v[16];
      *(uint4*)&v[0] = *(const uint4*)src;
      *(uint4*)&v[8] = *(const uint4*)(src + 8);
#pragma unroll
      for (int j = 0; j < 16; ++j) M.T[g * 16 + j][r] = v[j];
    }
    __syncthreads();
    {
      int d = tid >> 2, g = tid & 3;
      unsigned short* dst = Vtl + ((size_t)(b * LHH + h) * DH + d) * NN + n0 + g * 16;
      *(uint4*)dst       = *(uint4*)&M.T[d][g * 16];
      *(uint4*)(dst + 8) = *(uint4*)&M.T[d][g * 16 + 8];
    }
    return;
  }
  bid -= 1024;                                 /* kstab (2048 blocks) */
  {
    const int wid = tid >> 6, lane = tid & 63;
    const int quad = lane >> 4, l16 = lane & 15;
    const int chunk = bid & 63;
    const int bh = bid >> 6;
    const int b = bh >> 3, h = bh & 7;
    const int n0 = chunk * 64;
    const f32x4 zf = {0.f, 0.f, 0.f, 0.f};

    {
      const int r = tid >> 2, s2 = tid & 3;
      const size_t off = ((size_t)(b * NN + n0 + r)) * DMM + h * DH + s2 * 16;
      *(uint4*)&M.ks.Khh[r][s2 * 16]     = *(const uint4*)(KhH + off);
      *(uint4*)&M.ks.Khh[r][s2 * 16 + 8] = *(const uint4*)(KhH + off + 8);
      *(uint4*)&M.ks.Khl[r][s2 * 16]     = *(const uint4*)(KhL + off);
      *(uint4*)&M.ks.Khl[r][s2 * 16 + 8] = *(const uint4*)(KhL + off + 8);
    }
    __syncthreads();

    const int wn0 = wid * 64;
    f32x4 acc[4][4];
#pragma unroll
    for (int i = 0; i < 4; ++i)
#pragma unroll
      for (int j = 0; j < 4; ++j) acc[i][j] = zf;

#pragma unroll
    for (int ks = 0; ks < 2; ++ks) {
      fp16x8 afh[4], afl[4], bfh[4], bfl[4];
#pragma unroll
      for (int t = 0; t < 4; ++t) {
        afh[t] = *(const fp16x8*)&M.ks.Khh[t * 16 + l16][ks * 32 + quad * 8];
        afl[t] = *(const fp16x8*)&M.ks.Khl[t * 16 + l16][ks * 32 + quad * 8];
        const size_t po = (size_t)(wn0 + t * 16 + l16) * 64 + ks * 32 + quad * 8;
        bfh[t] = *(const fp16x8*)(phh + po);
        bfl[t] = *(const fp16x8*)(phl + po);
      }
#pragma unroll
      for (int mt = 0; mt < 4; ++mt)
#pragma unroll
        for (int nt = 0; nt < 4; ++nt) {
          acc[mt][nt] = __builtin_amdgcn_mfma_f32_16x16x32_f16(afh[mt], bfh[nt], acc[mt][nt], 0, 0, 0);
          acc[mt][nt] = __builtin_amdgcn_mfma_f32_16x16x32_f16(afh[mt], bfl[nt], acc[mt][nt], 0, 0, 0);
          acc[mt][nt] = __builtin_amdgcn_mfma_f32_16x16x32_f16(afl[mt], bfh[nt], acc[mt][nt], 0, 0, 0);
        }
    }

    float mx = -3.4e38f;
#pragma unroll
    for (int mt = 0; mt < 4; ++mt)
#pragma unroll
      for (int nt = 0; nt < 4; ++nt)
#pragma unroll
        for (int r = 0; r < 4; ++r) mx = fmaxf(mx, acc[mt][nt][r]);
#pragma unroll
    for (int off = 32; off; off >>= 1) mx = fmaxf(mx, __shfl_xor(mx, off));
    if (lane == 0) M.ks.wred[wid] = mx;
    __syncthreads();
    if (tid == 0)
      stabp[bid] = fmaxf(fmaxf(M.ks.wred[0], M.ks.wred[1]), fmaxf(M.ks.wred[2], M.ks.wred[3]));
  }
}

/* ---------------- reduce per-block maxima -> scalar stab ------------------- */
__global__ __launch_bounds__(256) void stab_reduce(
    const float* __restrict__ stabp, float* __restrict__ stab_f)
{
  __shared__ float wred[4];
  const int tid = threadIdx.x;
  float m = -3.4e38f;
  for (int i = tid; i < KSTAB_BLOCKS; i += 256) m = fmaxf(m, stabp[i]);
#pragma unroll
  for (int off = 32; off; off >>= 1) m = fmaxf(m, __shfl_xor(m, off));
  if ((tid & 63) == 0) wred[tid >> 6] = m;
  __syncthreads();
  if (tid == 0)
    *stab_f = fmaxf(fmaxf(wred[0], wred[1]), fmaxf(wred[2], wred[3]));
}

/* ---------------- FAVOR: context & k_sum partials via MFMA ----------------- */
__global__ __launch_bounds__(256, 2) void favor_ctx_mfma(
    const unsigned short* __restrict__ KhH, const unsigned short* __restrict__ KhL,
    const unsigned short* __restrict__ VhH,
    const unsigned short* __restrict__ phh, const unsigned short* __restrict__ phl,
    const float* __restrict__ stab_f,
    float* __restrict__ ctxp, float* __restrict__ ksump, int split)
{
  __shared__ unsigned short Khh[64][72];
  __shared__ unsigned short Khl[64][72];
  __shared__ unsigned short Vt_h[64][72];   /* [d][n] */
  __shared__ unsigned short kp_s[256][72];  /* [m][n] */
  __shared__ float diag_s[64];

  const int tid = threadIdx.x;
  const int wid = tid >> 6, lane = tid & 63;
  const int quad = lane >> 4, l16 = lane & 15;
  const int sidx = blockIdx.x % split;
  const int bh = blockIdx.x / split;
  const int b = bh >> 3, h = bh & 7;
  const int rows = NN / split, nch = rows / 64;
  const float stab = *stab_f;
  const int wn0 = wid * 64;
  const f32x4 zf = {0.f, 0.f, 0.f, 0.f};

  f32x4 acc2[4][4];
#pragma unroll
  for (int i = 0; i < 4; ++i)
#pragma unroll
    for (int j = 0; j < 4; ++j) acc2[i][j] = zf;
  float ksacc[4] = {0.f, 0.f, 0.f, 0.f};

  for (int c = 0; c < nch; ++c) {
    const int n0 = sidx * rows + c * 64;
    __syncthreads();
    {
      const int r = tid >> 2, s2 = tid & 3;
      const size_t off = ((size_t)(b * NN + n0 + r)) * DMM + h * DH + s2 * 16;
      unsigned short kh[16], kl[16], vv[16];
      *(uint4*)&kh[0] = *(const uint4*)(KhH + off);
      *(uint4*)&kh[8] = *(const uint4*)(KhH + off + 8);
      *(uint4*)&kl[0] = *(const uint4*)(KhL + off);
      *(uint4*)&kl[8] = *(const uint4*)(KhL + off + 8);
      *(uint4*)&vv[0] = *(const uint4*)(VhH + off);
      *(uint4*)&vv[8] = *(const uint4*)(VhH + off + 8);
      float kq = 0.f;
#pragma unroll
      for (int j = 0; j < 16; ++j) {
        float f = h2f(kh[j]) + h2f(kl[j]);
        kq = fmaf(f, f, kq);
        Vt_h[s2 * 16 + j][r] = vv[j];
      }
      *(uint4*)&Khh[r][s2 * 16]     = *(uint4*)&kh[0];
      *(uint4*)&Khh[r][s2 * 16 + 8] = *(uint4*)&kh[8];
      *(uint4*)&Khl[r][s2 * 16]     = *(uint4*)&kl[0];
      *(uint4*)&Khl[r][s2 * 16 + 8] = *(uint4*)&kl[8];
      kq += __shfl_xor(kq, 1);
      kq += __shfl_xor(kq, 2);
      if (s2 == 0) diag_s[r] = 0.5f * NRM2 * kq;
    }
    __syncthreads();

    f32x4 acc[4][4];
#pragma unroll
    for (int i = 0; i < 4; ++i)
#pragma unroll
      for (int j = 0; j < 4; ++j) acc[i][j] = zf;
#pragma unroll
    for (int ks = 0; ks < 2; ++ks) {
      fp16x8 afh[4], afl[4], bfh[4], bfl[4];
#pragma unroll
      for (int t = 0; t < 4; ++t) {
        afh[t] = *(const fp16x8*)&Khh[t * 16 + l16][ks * 32 + quad * 8];
        afl[t] = *(const fp16x8*)&Khl[t * 16 + l16][ks * 32 + quad * 8];
        const size_t po = (size_t)(wn0 + t * 16 + l16) * 64 + ks * 32 + quad * 8;
        bfh[t] = *(const fp16x8*)(phh + po);
        bfl[t] = *(const fp16x8*)(phl + po);
      }
#pragma unroll
      for (int mt = 0; mt < 4; ++mt)
#pragma unroll
        for (int nt = 0; nt < 4; ++nt) {
          acc[mt][nt] = __builtin_amdgcn_mfma_f32_16x16x32_f16(afh[mt], bfh[nt], acc[mt][nt], 0, 0, 0);
          acc[mt][nt] = __builtin_amdgcn_mfma_f32_16x16x32_f16(afh[mt], bfl[nt], acc[mt][nt], 0, 0, 0);
          acc[mt][nt] = __builtin_amdgcn_mfma_f32_16x16x32_f16(afl[mt], bfh[nt], acc[mt][nt], 0, 0, 0);
        }
    }

    float ks_i[4] = {0.f, 0.f, 0.f, 0.f};
#pragma unroll
    for (int mt = 0; mt < 4; ++mt) {
#pragma unroll
      for (int nt = 0; nt < 4; ++nt) {
        float pv[4];
#pragma unroll
        for (int reg = 0; reg < 4; ++reg) {
          const int n = mt * 16 + quad * 4 + reg;
          float p = RATIO * (__expf(acc[mt][nt][reg] - diag_s[n] - stab) + EPSF);
          pv[reg] = p;
          ks_i[nt] += p;
        }
        __half2 h0 = __floats2half2_rn(pv[0], pv[1]);
        __half2 h1 = __floats2half2_rn(pv[2], pv[3]);
        uint2 w;
        w.x = *(unsigned*)&h0;
        w.y = *(unsigned*)&h1;
        *(uint2*)&kp_s[wn0 + nt * 16 + l16][mt * 16 + quad * 4] = w;
      }
    }
#pragma unroll
    for (int nt = 0; nt < 4; ++nt) {
      float s = ks_i[nt];
      s += __shfl_xor(s, 16);
      s += __shfl_xor(s, 32);
      ksacc[nt] += s;
    }
    __syncthreads();

#pragma unroll
    for (int ks2 = 0; ks2 < 2; ++ks2) {
      fp16x8 ap[4], bv[4];
#pragma unroll
      for (int t = 0; t < 4; ++t) {
        ap[t] = *(const fp16x8*)&kp_s[wn0 + t * 16 + l16][ks2 * 32 + quad * 8];
        bv[t] = *(const fp16x8*)&Vt_h[t * 16 + l16][ks2 * 32 + quad * 8];
      }
#pragma unroll
      for (int mt = 0; mt < 4; ++mt)
#pragma unroll
        for (int nt = 0; nt < 4; ++nt)
          acc2[mt][nt] = __builtin_amdgcn_mfma_f32_16x16x32_f16(ap[mt], bv[nt], acc2[mt][nt], 0, 0, 0);
    }
  }

  {
    float* dst = ctxp + ((size_t)(bh * split + sidx)) * MM * DH;
#pragma unroll
    for (int mt = 0; mt < 4; ++mt)
#pragma unroll
      for (int nt = 0; nt < 4; ++nt) {
        const int m = wn0 + mt * 16 + quad * 4;
        const int d = nt * 16 + l16;
        *(f32x4*)(dst + (size_t)d * MM + m) = acc2[mt][nt];
      }
    if (quad == 0) {
      float* kd = ksump + (size_t)(bh * split + sidx) * MM;
#pragma unroll
      for (int nt = 0; nt < 4; ++nt) kd[wn0 + nt * 16 + l16] = ksacc[nt];
    }
  }
}

/* ---------------- FAVOR: reduce partials -> ctxT fp16 [bh][d][m] + ksum ---- */
__global__ __launch_bounds__(256) void favor_reduce(
    const float* __restrict__ ctxp, const float* __restrict__ ksump,
    unsigned short* __restrict__ ctxT_h, float* __restrict__ ksum, int split)
{
  int i = blockIdx.x * 256 + threadIdx.x;
  if (i < BB * GHH * MM * DH) {
    int bh = i / (MM * DH);
    int md = i % (MM * DH);
    float s = 0.f;
    for (int k = 0; k < split; ++k) s += ctxp[((size_t)(bh * split + k)) * MM * DH + md];
    ctxT_h[i] = f2h(s);
  }
  if (i < BB * GHH * MM) {
    int bh = i / MM, m = i % MM;
    float s = 0.f;
    for (int k = 0; k < split; ++k) s += ksump[(bh * split + k) * MM + m];
    ksum[i] = s;
  }
}

/* ---------------- FAVOR fused output via MFMA (LDS-union, 4 blocks/CU) ----- */
__global__ __launch_bounds__(256, 4) void favor_out_mfma(
    const unsigned short* __restrict__ QhH, const unsigned short* __restrict__ QhL,
    const unsigned short* __restrict__ phh, const unsigned short* __restrict__ phl,
    const unsigned short* __restrict__ ctxT_h, const float* __restrict__ ksum,
    unsigned short* __restrict__ xH, unsigned short* __restrict__ xL)
{
  __shared__ union {
    struct { unsigned short Qhh[64][72]; unsigned short Qhl[64][72]; } a;
    unsigned short qp[64][264];
  } sm;
  __shared__ float red[4][64];
  __shared__ float dred[4][64];
  __shared__ float diag4[64][4];
  __shared__ float diag_s[64];
  __shared__ float dinv_s[64];
  __shared__ float ksum_s[256];

  const int tid = threadIdx.x;
  const int wid = tid >> 6, lane = tid & 63;
  const int quad = lane >> 4, l16 = lane & 15;
  const int bh = blockIdx.x >> 6;
  const int chunk = blockIdx.x & 63;
  const int b = bh >> 3, h = bh & 7;
  const int n0 = chunk * 64;
  const f32x4 zf = {0.f, 0.f, 0.f, 0.f};

  /* load Q chunk from planes; diag partials from hi+lo */
  {
    const int r = tid >> 2, s2 = tid & 3;
    const size_t off = ((size_t)(b * NN + n0 + r)) * DMM + h * DH + s2 * 16;
    unsigned short qh[16], ql[16];
    *(uint4*)&qh[0] = *(const uint4*)(QhH + off);
    *(uint4*)&qh[8] = *(const uint4*)(QhH + off + 8);
    *(uint4*)&ql[0] = *(const uint4*)(QhL + off);
    *(uint4*)&ql[8] = *(const uint4*)(QhL + off + 8);
    float sq = 0.f;
#pragma unroll
    for (int j = 0; j < 16; ++j) {
      float f = h2f(qh[j]) + h2f(ql[j]);
      sq = fmaf(f, f, sq);
    }
    diag4[r][s2] = sq;
    *(uint4*)&sm.a.Qhh[r][s2 * 16]     = *(uint4*)&qh[0];
    *(uint4*)&sm.a.Qhh[r][s2 * 16 + 8] = *(uint4*)&qh[8];
    *(uint4*)&sm.a.Qhl[r][s2 * 16]     = *(uint4*)&ql[0];
    *(uint4*)&sm.a.Qhl[r][s2 * 16 + 8] = *(uint4*)&ql[8];
    ksum_s[tid] = ksum[bh * MM + tid];
  }
  __syncthreads();
  if (tid < 64)
    diag_s[tid] = 0.5f * NRM2 * (diag4[tid][0] + diag4[tid][1] + diag4[tid][2] + diag4[tid][3]);

  /* dd GEMM: rows 64 x wave's 64 feature-cols, K=64, split-fp16 (hh+hl+lh) */
  const int wn0 = wid * 64;
  f32x4 acc[4][4];
#pragma unroll
  for (int i = 0; i < 4; ++i)
#pragma unroll
    for (int j = 0; j < 4; ++j) acc[i][j] = zf;

#pragma unroll
  for (int ks = 0; ks < 2; ++ks) {
    fp16x8 afh[4], afl[4], bfh[4], bfl[4];
#pragma unroll
    for (int t = 0; t < 4; ++t) {
      afh[t] = *(const fp16x8*)&sm.a.Qhh[t * 16 + l16][ks * 32 + quad * 8];
      afl[t] = *(const fp16x8*)&sm.a.Qhl[t * 16 + l16][ks * 32 + quad * 8];
      const size_t po = (size_t)(wn0 + t * 16 + l16) * 64 + ks * 32 + quad * 8;
      bfh[t] = *(const fp16x8*)(phh + po);
      bfl[t] = *(const fp16x8*)(phl + po);
    }
#pragma unroll
    for (int mt = 0; mt < 4; ++mt)
#pragma unroll
      for (int nt = 0; nt < 4; ++nt) {
        acc[mt][nt] = __builtin_amdgcn_mfma_f32_16x16x32_f16(afh[mt], bfh[nt], acc[mt][nt], 0, 0, 0);
        acc[mt][nt] = __builtin_amdgcn_mfma_f32_16x16x32_f16(afh[mt], bfl[nt], acc[mt][nt], 0, 0, 0);
        acc[mt][nt] = __builtin_amdgcn_mfma_f32_16x16x32_f16(afl[mt], bfh[nt], acc[mt][nt], 0, 0, 0);
      }
  }

  /* per-row wave-local max -> LDS */
#pragma unroll
  for (int mt = 0; mt < 4; ++mt)
#pragma unroll
    for (int reg = 0; reg < 4; ++reg) {
      float v = fmaxf(fmaxf(acc[mt][0][reg], acc[mt][1][reg]),
                      fmaxf(acc[mt][2][reg], acc[mt][3][reg]));
      v = fmaxf(v, __shfl_xor(v, 1));
      v = fmaxf(v, __shfl_xor(v, 2));
      v = fmaxf(v, __shfl_xor(v, 4));
      v = fmaxf(v, __shfl_xor(v, 8));
      if (l16 == 0) red[wid][mt * 16 + quad * 4 + reg] = v;
    }
  __syncthreads();   /* all Qhh/Qhl reads drained -> qp aliasing safe */

  /* qp = RATIO*(exp(dd - diag - stab) + EPS); dsum partials; qp -> fp16 LDS */
  float ksv[4];
#pragma unroll
  for (int nt = 0; nt < 4; ++nt) ksv[nt] = ksum_s[wn0 + nt * 16 + l16];
#pragma unroll
  for (int mt = 0; mt < 4; ++mt)
#pragma unroll
    for (int reg = 0; reg < 4; ++reg) {
      const int row = mt * 16 + quad * 4 + reg;
      float stab = fmaxf(fmaxf(red[0][row], red[1][row]),
                         fmaxf(red[2][row], red[3][row]));
      float base = diag_s[row] + stab;
      float dsum = 0.f;
#pragma unroll
      for (int nt = 0; nt < 4; ++nt) {
        float p = RATIO * (__expf(acc[mt][nt][reg] - base) + EPSF);
        acc[mt][nt][reg] = p;
        dsum = fmaf(p, ksv[nt], dsum);
      }
      dsum += __shfl_xor(dsum, 1);
      dsum += __shfl_xor(dsum, 2);
      dsum += __shfl_xor(dsum, 4);
      dsum += __shfl_xor(dsum, 8);
      if (l16 == 0) dred[wid][row] = dsum;
#pragma unroll
      for (int nt = 0; nt < 4; ++nt)
        sm.qp[row][wn0 + nt * 16 + l16] = f2h(acc[mt][nt][reg]);
    }
  __syncthreads();
  if (tid < 64)
    dinv_s[tid] = 1.0f / (dred[0][tid] + dred[1][tid] + dred[2][tid] + dred[3][tid]);

  /* PV: out[64 x wave's 16 d-cols] = qp[64x256] @ ctxT rows, K=256 */
  const int wn2 = wid * 16;
  f32x4 acc2[4];
#pragma unroll
  for (int mt = 0; mt < 4; ++mt) acc2[mt] = zf;
#pragma unroll
  for (int ksp = 0; ksp < 8; ++ksp) {
    fp16x8 bv = *(const fp16x8*)(ctxT_h + ((size_t)bh * DH + wn2 + l16) * MM + ksp * 32 + quad * 8);
    fp16x8 ap[4];
#pragma unroll
    for (int mt = 0; mt < 4; ++mt)
      ap[mt] = *(const fp16x8*)&sm.qp[mt * 16 + l16][ksp * 32 + quad * 8];
#pragma unroll
    for (int mt = 0; mt < 4; ++mt)
      acc2[mt] = __builtin_amdgcn_mfma_f32_16x16x32_f16(ap[mt], bv, acc2[mt], 0, 0, 0);
  }
  __syncthreads();

  /* epilogue: scale by 1/dsum, split-fp16 into xH/xL */
#pragma unroll
  for (int mt = 0; mt < 4; ++mt)
#pragma unroll
    for (int reg = 0; reg < 4; ++reg) {
      const int row = mt * 16 + quad * 4 + reg;
      float o = acc2[mt][reg] * dinv_s[row];
      const size_t base = ((size_t)(b * NN + n0 + row)) * DMM + h * DH + wn2 + l16;
      unsigned short hi = f2h(o);
      xH[base] = hi;
      xL[base] = f2h(o - h2f(hi));
    }
}

/* ---------------- local attention via f16 MFMA (flash-style) --------------- */
__global__ __launch_bounds__(256) void local_attn2(
    const unsigned short* __restrict__ Qlh, const unsigned short* __restrict__ Klh,
    const unsigned short* __restrict__ Vt,
    unsigned short* __restrict__ xH, unsigned short* __restrict__ xL)
{
  __shared__ unsigned short Pl[4][32][72];
  const int w = blockIdx.x, h = blockIdx.y, b = blockIdx.z;
  const int tid = threadIdx.x;
  const int wid = tid >> 6, lane = tid & 63;
  const int quad = lane >> 4, l16 = lane & 15;
  const int bh = b * LHH + h;
  const int qn0 = w * WW + wid * 32;

  fp16x8 Aq[2][2];
#pragma unroll
  for (int mt = 0; mt < 2; ++mt)
#pragma unroll
    for (int ks = 0; ks < 2; ++ks)
      Aq[mt][ks] = *(const fp16x8*)(Qlh + ((size_t)bh * NN + qn0 + mt * 16 + l16) * 64 + ks * 32 + quad * 8);

  float m_run[8], l_run[8];
  f32x4 Oacc[2][4];
  const f32x4 zf = {0.f, 0.f, 0.f, 0.f};
#pragma unroll
  for (int r = 0; r < 8; ++r) { m_run[r] = -3.4e38f; l_run[r] = 0.f; }
#pragma unroll
  for (int mt = 0; mt < 2; ++mt)
#pragma unroll
    for (int nt = 0; nt < 4; ++nt) Oacc[mt][nt] = zf;

  const int wb_lo = (w == 0) ? 0 : w - 1;
  const int wb_hi = (w == NWIN - 1) ? w : w + 1;
  for (int wb = wb_lo; wb <= wb_hi; ++wb) {
    for (int half = 0; half < 2; ++half) {
      const int kn0 = wb * WW + half * 64;
      f32x4 sacc[2][4];
#pragma unroll
      for (int mt = 0; mt < 2; ++mt)
#pragma unroll
        for (int nt = 0; nt < 4; ++nt) sacc[mt][nt] = zf;

#pragma unroll
      for (int ks = 0; ks < 2; ++ks) {
        fp16x8 Bk[4];
#pragma unroll
        for (int nt = 0; nt < 4; ++nt)
          Bk[nt] = *(const fp16x8*)(Klh + ((size_t)bh * NN + kn0 + nt * 16 + l16) * 64 + ks * 32 + quad * 8);
#pragma unroll
        for (int mt = 0; mt < 2; ++mt)
#pragma unroll
          for (int nt = 0; nt < 4; ++nt)
            sacc[mt][nt] = __builtin_amdgcn_mfma_f32_16x16x32_f16(Aq[mt][ks], Bk[nt], sacc[mt][nt], 0, 0, 0);
      }

      /* online softmax per row (row = mt*16 + quad*4 + reg) */
#pragma unroll
      for (int mt = 0; mt < 2; ++mt) {
#pragma unroll
        for (int reg = 0; reg < 4; ++reg) {
          const int r8 = mt * 4 + reg;
          float v = fmaxf(fmaxf(sacc[mt][0][reg], sacc[mt][1][reg]),
                          fmaxf(sacc[mt][2][reg], sacc[mt][3][reg]));
          v = fmaxf(v, __shfl_xor(v, 1));
          v = fmaxf(v, __shfl_xor(v, 2));
          v = fmaxf(v, __shfl_xor(v, 4));
          v = fmaxf(v, __shfl_xor(v, 8));
          float mnew = fmaxf(m_run[r8], v);
          float alpha = __expf(m_run[r8] - mnew);
          m_run[r8] = mnew;
          float ps = 0.f;
#pragma unroll
          for (int nt = 0; nt < 4; ++nt) {
            float p = __expf(sacc[mt][nt][reg] - mnew);
            sacc[mt][nt][reg] = p;
            ps += p;
          }
          ps += __shfl_xor(ps, 1);
          ps += __shfl_xor(ps, 2);
          ps += __shfl_xor(ps, 4);
          ps += __shfl_xor(ps, 8);
          l_run[r8] = l_run[r8] * alpha + ps;
#pragma unroll
          for (int nt = 0; nt < 4; ++nt) Oacc[mt][nt][reg] *= alpha;
        }
      }

      /* write P fp16 (C-layout -> [qrow][key] in LDS, wave-local) */
#pragma unroll
      for (int mt = 0; mt < 2; ++mt)
#pragma unroll
        for (int nt = 0; nt < 4; ++nt)
#pragma unroll
          for (int reg = 0; reg < 4; ++reg)
            Pl[wid][mt * 16 + quad * 4 + reg][nt * 16 + l16] = f2h(sacc[mt][nt][reg]);

      /* PV */
#pragma unroll
      for (int kstep = 0; kstep < 2; ++kstep) {
        fp16x8 Ap[2];
#pragma unroll
        for (int mt = 0; mt < 2; ++mt)
          Ap[mt] = *(const fp16x8*)&Pl[wid][mt * 16 + l16][kstep * 32 + quad * 8];
        fp16x8 Bv[4];
#pragma unroll
        for (int nt = 0; nt < 4; ++nt)
          Bv[nt] = *(const fp16x8*)(Vt + ((size_t)bh * DH + nt * 16 + l16) * NN + kn0 + kstep * 32 + quad * 8);
#pragma unroll
        for (int mt = 0; mt < 2; ++mt)
#pragma unroll
          for (int nt = 0; nt < 4; ++nt)
            Oacc[mt][nt] = __builtin_amdgcn_mfma_f32_16x16x32_f16(Ap[mt], Bv[nt], Oacc[mt][nt], 0, 0, 0);
      }
    }
  }

  /* epilogue: divide by l, split-fp16 into xH/xL local-head columns */
#pragma unroll
  for (int mt = 0; mt < 2; ++mt)
#pragma unroll
    for (int reg = 0; reg < 4; ++reg) {
      const float inv = 1.0f / l_run[mt * 4 + reg];
      const int n = qn0 + mt * 16 + quad * 4 + reg;
      const size_t base = ((size_t)(b * NN + n)) * DMM + GHH * DH + h * DH;
#pragma unroll
      for (int nt = 0; nt < 4; ++nt) {
        float o = Oacc[mt][nt][reg] * inv;
        unsigned short hi = f2h(o);
        xH[base + nt * 16 + l16] = hi;
        xL[base + nt * 16 + l16] = f2h(o - h2f(hi));
      }
    }
}

/* ---------------- launcher -------------------------------------------------- */
extern "C" void kernel_launch(void* const* d_in, const int* in_sizes, int n_in,
                              void* d_out, int out_size, void* d_ws, size_t ws_size,
                              hipStream_t stream)
{
  (void)in_sizes; (void)n_in; (void)out_size;
  const float* x    = (const float*)d_in[0];
  const float* Wq   = (const float*)d_in[2];
  const float* Wk   = (const float*)d_in[3];
  const float* Wv   = (const float*)d_in[4];
  const float* Wo   = (const float*)d_in[5];
  const float* bo   = (const float*)d_in[6];
  const float* proj = (const float*)d_in[7];
  float* out = (float*)d_out;

  const size_t WSZ = (size_t)DMM * DMM;
  const size_t XSP = (size_t)BB * NN * DMM;
  const size_t wbuf_f = (4 * WSZ * 2 + 3) / 4;
  const size_t LSZ = (size_t)BB * LHH * NN * DH;
  const size_t lbuf_f = (3 * LSZ * 2 + 3) / 4;
  const size_t fixed_f = (size_t)3 * XSP + (size_t)BB * GHH * MM * DH
                       + (size_t)BB * GHH * MM + KSTAB_BLOCKS + 16 + MM * DH + 16
                       + wbuf_f + 16 + lbuf_f + 16;

  int split = 8;
  for (int s = 32; s >= 8; s >>= 1) {
    size_t part = (size_t)BB * GHH * s * (MM * DH + MM);
    size_t region = part > XSP ? part : XSP;
    if ((fixed_f + region) * 4 <= ws_size) { split = s; break; }
  }
  size_t part_f = (size_t)BB * GHH * split * (MM * DH + MM);
  size_t region_f = XSP > part_f ? XSP : part_f;

  unsigned short* QhH = (unsigned short*)d_ws;
  unsigned short* QhL = QhH + XSP;
  unsigned short* KhH = QhH + 2 * XSP;
  unsigned short* KhL = QhH + 3 * XSP;
  unsigned short* VhH = QhH + 4 * XSP;
  float* region = (float*)d_ws + 3 * XSP;
  float* ctxp  = region;
  float* ksump = ctxp + (size_t)BB * GHH * split * MM * DH;
  unsigned short* xH = (unsigned short*)region;
  unsigned short* xL = xH + XSP;
  float* ctx   = region + region_f;
  unsigned short* ctxT_h = (unsigned short*)ctx;
  float* ksum  = ctx + (size_t)BB * GHH * MM * DH;
  float* stabp = ksum + BB * GHH * MM;
  float* stab_f = stabp + KSTAB_BLOCKS;
  unsigned short* proj_hh = (unsigned short*)(stab_f + 16);
  unsigned short* proj_hl = proj_hh + MM * DH;
  unsigned short* wsp = proj_hl + MM * DH;
  unsigned short* WqH = wsp;
  unsigned short* WkH = wsp + WSZ;
  unsigned short* WvH = wsp + 2 * WSZ;
  unsigned short* WoH = wsp + 3 * WSZ;
  unsigned short* Qlh = wsp + 4 * WSZ;
  unsigned short* Klh = Qlh + LSZ;
  unsigned short* Vtl = Klh + LSZ;

  dim3 blk(256);
  dim3 mg(DMM / 128, (BB * NN) / 128);
  const int PREP_BLOCKS = 4 * WGRID + AGRID + 64;
  const int MID_BLOCKS  = 256 + 1024 + KSTAB_BLOCKS;

  prep_all<<<PREP_BLOCKS, blk, 0, stream>>>(Wq, Wk, Wv, Wo, x, proj,
                                            WqH, WkH, WvH, WoH, xH, xL,
                                            proj_hh, proj_hl);
  gemm_mfma_sp<<<mg, blk, 0, stream>>>(xH, xL, WqH, QhH, QhL, DMM, DMM);
  gemm_mfma_sp<<<mg, blk, 0, stream>>>(xH, xL, WkH, KhH, KhL, DMM, DMM);
  gemm_mfma_sp<<<mg, blk, 0, stream>>>(xH, xL, WvH, VhH, (unsigned short*)0, DMM, DMM);
  mid_all<<<MID_BLOCKS, blk, 0, stream>>>(QhH, KhH, KhL, VhH, proj_hh, proj_hl,
                                          Qlh, Klh, Vtl, stabp);
  stab_reduce<<<1, blk, 0, stream>>>(stabp, stab_f);
  favor_ctx_mfma<<<BB * GHH * split, blk, 0, stream>>>(KhH, KhL, VhH, proj_hh, proj_hl,
                                                       stab_f, ctxp, ksump, split);
  favor_reduce<<<(BB * GHH * MM * DH) / 256, blk, 0, stream>>>(ctxp, ksump, ctxT_h, ksum, split);
  favor_out_mfma<<<BB * GHH * (NN / 64), blk, 0, stream>>>(QhH, QhL, proj_hh, proj_hl,
                                                           ctxT_h, ksum, xH, xL);
  local_attn2<<<dim3(NWIN, LHH, BB), blk, 0, stream>>>(Qlh, Klh, Vtl, xH, xL);
  gemm_mfma_pre<<<mg, blk, 0, stream>>>(xH, xL, WoH, bo, out, DMM, DMM);
}